// Round 5
// baseline (936.997 us; speedup 1.0000x reference)
//
#include <hip/hip_runtime.h>
#include <stdint.h>

typedef _Float16 half_t;
typedef __attribute__((ext_vector_type(4))) _Float16 half4;
typedef __attribute__((ext_vector_type(8))) _Float16 half8;
typedef __attribute__((ext_vector_type(4))) float f32x4;

#define N_TOK 8192
#define H_DIM 1024
#define D_DIM 512
#define NE 8
#define NL 3

#define WAITV6 asm volatile("s_waitcnt vmcnt(6)" ::: "memory")
#define WAITV3 asm volatile("s_waitcnt vmcnt(3)" ::: "memory")
#define WAITV0 asm volatile("s_waitcnt vmcnt(0)" ::: "memory")
#define SCHEDB __builtin_amdgcn_sched_barrier(0)
#define RAWBAR __builtin_amdgcn_s_barrier()

// -------- async global->LDS, 16B per lane, linear dest --------
__device__ __forceinline__ void gload_lds16(const half_t* g, half_t* l) {
  __builtin_amdgcn_global_load_lds(
      (const __attribute__((address_space(1))) unsigned int*)g,
      (__attribute__((address_space(3))) unsigned int*)l, 16, 0, 0);
}

// -------- init: softmax over hierarchical weights + zero counters --------
__global__ void init_small(const float* __restrict__ w, float* __restrict__ hwp,
                           int* __restrict__ cnt) {
  const int t = threadIdx.x;
  if (t < NL * NE) cnt[t] = 0;
  if (t == 0) {
    float m = fmaxf(fmaxf(w[0], w[1]), w[2]);
    float e0 = expf(w[0] - m), e1 = expf(w[1] - m), e2 = expf(w[2] - m);
    float s = e0 + e1 + e2;
    hwp[0] = e0 / s; hwp[1] = e1 / s; hwp[2] = e2 / s;
  }
}

// -------- fp32 [R][C] -> f16 transposed [C][R], optional scaled-lo output --------
__global__ void transpose_cvt(const float* __restrict__ in, unsigned long long in_zs,
                              half_t* __restrict__ oh, half_t* __restrict__ ol,
                              unsigned long long out_zs, int R, int C) {
  __shared__ float tile[64][65];
  const float* src = in + (size_t)blockIdx.z * in_zs;
  const int rt = blockIdx.x * 64;
  const int ct = blockIdx.y * 64;
  const int tid = threadIdx.x;
  const int r = tid >> 2, c0 = (tid & 3) * 16;
  const float* p = src + (size_t)(rt + r) * C + ct + c0;
#pragma unroll
  for (int q = 0; q < 4; ++q) {
    float4 v = *(const float4*)(p + q * 4);
    tile[r][c0 + q * 4 + 0] = v.x;
    tile[r][c0 + q * 4 + 1] = v.y;
    tile[r][c0 + q * 4 + 2] = v.z;
    tile[r][c0 + q * 4 + 3] = v.w;
  }
  __syncthreads();
  const int nl = tid >> 2, k0 = (tid & 3) * 16;
  half8 hv0, hv1, lv0, lv1;
#pragma unroll
  for (int i = 0; i < 16; ++i) {
    float v = tile[k0 + i][nl];
    half_t h = (half_t)v;
    half_t lo = (half_t)((v - (float)h) * 2048.f);
    if (i < 8) { hv0[i] = h; lv0[i] = lo; } else { hv1[i - 8] = h; lv1[i - 8] = lo; }
  }
  half_t* dst = oh + (size_t)blockIdx.z * out_zs + (size_t)(ct + nl) * R + rt + k0;
  *(half8*)dst = hv0;
  *(half8*)(dst + 8) = hv1;
  if (ol) {
    half_t* dstl = ol + (size_t)blockIdx.z * out_zs + (size_t)(ct + nl) * R + rt + k0;
    *(half8*)dstl = lv0;
    *(half8*)(dstl + 8) = lv1;
  }
}

// -------- fp32 x -> f16 hi + scaled lo --------
__global__ void cvt_x_hilo(const float* __restrict__ in, half_t* __restrict__ oh,
                           half_t* __restrict__ ol, int n4) {
  int i = blockIdx.x * blockDim.x + threadIdx.x;
  if (i < n4) {
    float4 v = ((const float4*)in)[i];
    float vv[4] = {v.x, v.y, v.z, v.w};
    half4 hv, lv;
#pragma unroll
    for (int j = 0; j < 4; ++j) {
      half_t h = (half_t)vv[j];
      hv[j] = h;
      lv[j] = (half_t)((vv[j] - (float)h) * 2048.f);
    }
    ((half4*)oh)[i] = hv;
    ((half4*)ol)[i] = lv;
  }
}

// -------- router GEMM: h = relu(x @ w1 + b1), fp16-split 3-pass MFMA --------
// A: x hi/lo [8192][1024]; B: w1^T hi/lo [512][1024]; BM=128 BN=64 BK=32
// depth-2 pipeline: 3 LDS buffers, counted vmcnt, raw barriers.
// buffer layout (halves): Ah[0,4096) Al[4096,8192) Bh[8192,10240) Bl[10240,12288)
__global__ __launch_bounds__(256, 2) void routing_gemm(
    const half_t* __restrict__ xh, const half_t* __restrict__ xl,
    const half_t* __restrict__ wh, const half_t* __restrict__ wl,
    const float* __restrict__ b1, float* __restrict__ hout) {
  __shared__ __align__(16) half_t lds[3 * 12288];
  const int tid = threadIdx.x;
  const int lane = tid & 63;
  const int wv = tid >> 6;
  const int wm = wv >> 1, wn = wv & 1;
  const int mt = blockIdx.x, nt = blockIdx.y;

  const int srow = tid >> 2;
  const int skc = (tid & 3) * 8;
  const size_t abase = (size_t)(mt * 128 + srow) * H_DIM + skc;
  const half_t* gAh = xh + abase;
  const half_t* gAl = xl + abase;
  const size_t bbase = (size_t)(nt * 64 + srow) * H_DIM + skc;
  const half_t* gBh = wh + bbase;
  const half_t* gBl = wl + bbase;
  const size_t half_stride = (size_t)64 * H_DIM;

  f32x4 accM[4][2], accX[4][2];
#pragma unroll
  for (int m = 0; m < 4; ++m)
#pragma unroll
    for (int n = 0; n < 2; ++n) {
      accM[m][n] = {0.f, 0.f, 0.f, 0.f};
      accX[m][n] = {0.f, 0.f, 0.f, 0.f};
    }

  const int fr = lane & 15, fg = lane >> 4;
  const int aoff = (wm * 64 + fr) * 32 + fg * 8;
  const int boff = 8192 + (wn * 32 + fr) * 32 + fg * 8;

#define R_STAGE(bo, kk) do { \
    const int go_ = (kk) * 32; \
    gload_lds16(gAh + go_, lds + (bo) + tid * 8); \
    gload_lds16(gAh + go_ + half_stride, lds + (bo) + 2048 + tid * 8); \
    gload_lds16(gAl + go_, lds + (bo) + 4096 + tid * 8); \
    gload_lds16(gAl + go_ + half_stride, lds + (bo) + 4096 + 2048 + tid * 8); \
    gload_lds16(gBh + go_, lds + (bo) + 8192 + tid * 8); \
    gload_lds16(gBl + go_, lds + (bo) + 10240 + tid * 8); \
  } while (0)

  R_STAGE(0, 0);
  R_STAGE(12288, 1);
  int cur = 0;
  for (int k = 0; k < 32; ++k) {
    if (k < 31) { WAITV6; } else { WAITV0; }
    SCHEDB;
    RAWBAR;
    SCHEDB;
    if (k + 2 < 32) {
      int nxt = cur + 2; if (nxt >= 3) nxt -= 3;
      R_STAGE(nxt * 12288, k + 2);
    }
    const int cb = cur * 12288;
    half8 a_h[4], a_l[4], b_h[2], b_l[2];
#pragma unroll
    for (int m = 0; m < 4; ++m) {
      a_h[m] = *(const half8*)&lds[cb + aoff + m * 16 * 32];
      a_l[m] = *(const half8*)&lds[cb + 4096 + aoff + m * 16 * 32];
    }
#pragma unroll
    for (int n = 0; n < 2; ++n) {
      b_h[n] = *(const half8*)&lds[cb + boff + n * 16 * 32];
      b_l[n] = *(const half8*)&lds[cb + 2048 + boff + n * 16 * 32];
    }
#pragma unroll
    for (int m = 0; m < 4; ++m)
#pragma unroll
      for (int n = 0; n < 2; ++n) {
        accM[m][n] = __builtin_amdgcn_mfma_f32_16x16x32_f16(a_h[m], b_h[n], accM[m][n], 0, 0, 0);
        accX[m][n] = __builtin_amdgcn_mfma_f32_16x16x32_f16(a_h[m], b_l[n], accX[m][n], 0, 0, 0);
        accX[m][n] = __builtin_amdgcn_mfma_f32_16x16x32_f16(a_l[m], b_h[n], accX[m][n], 0, 0, 0);
      }
    SCHEDB;
    cur = (cur == 2) ? 0 : cur + 1;
  }
#undef R_STAGE

  const float inv = 1.0f / 2048.0f;
#pragma unroll
  for (int m = 0; m < 4; ++m) {
    const int row0 = mt * 128 + wm * 64 + m * 16 + fg * 4;
#pragma unroll
    for (int n = 0; n < 2; ++n) {
      const int col = nt * 64 + wn * 32 + n * 16 + fr;
      const float bv = b1[col];
#pragma unroll
      for (int r = 0; r < 4; ++r) {
        float v = accM[m][n][r] + accX[m][n][r] * inv + bv;
        hout[(size_t)(row0 + r) * D_DIM + col] = fmaxf(v, 0.f);
      }
    }
  }
}

// -------- logits + argmax + per-expert count; one wave per token --------
__global__ void logits_argmax(const float* __restrict__ hbuf, const float* __restrict__ w2,
                              const float* __restrict__ b2, int* __restrict__ eidx,
                              int* __restrict__ cnt) {
  const int tid = threadIdx.x, lane = tid & 63, wv = tid >> 6;
  const int t = blockIdx.x * 4 + wv;
  const float* hr = hbuf + (size_t)t * D_DIM;
  float4 h0 = *(const float4*)(hr + lane * 8);
  float4 h1 = *(const float4*)(hr + lane * 8 + 4);
  float p[8] = {0, 0, 0, 0, 0, 0, 0, 0};
  const float* wr = w2 + (size_t)lane * 8 * 8;
  float hv[8] = {h0.x, h0.y, h0.z, h0.w, h1.x, h1.y, h1.z, h1.w};
#pragma unroll
  for (int j = 0; j < 8; ++j) {
    float4 wa = *(const float4*)(wr + j * 8);
    float4 wb = *(const float4*)(wr + j * 8 + 4);
    p[0] += hv[j] * wa.x; p[1] += hv[j] * wa.y; p[2] += hv[j] * wa.z; p[3] += hv[j] * wa.w;
    p[4] += hv[j] * wb.x; p[5] += hv[j] * wb.y; p[6] += hv[j] * wb.z; p[7] += hv[j] * wb.w;
  }
#pragma unroll
  for (int o = 32; o > 0; o >>= 1) {
#pragma unroll
    for (int e = 0; e < 8; ++e) p[e] += __shfl_xor(p[e], o, 64);
  }
  if (lane == 0) {
    int best = 0;
    float bvv = p[0] + b2[0];
#pragma unroll
    for (int e = 1; e < 8; ++e) {
      float v = p[e] + b2[e];
      if (v > bvv) { bvv = v; best = e; }
    }
    eidx[t] = best;
    atomicAdd(&cnt[best], 1);
  }
}

__global__ void scan8(const int* __restrict__ cnt, int* __restrict__ offs, int* __restrict__ cur) {
  if (threadIdx.x == 0) {
    int a = 0;
    for (int i = 0; i < 8; ++i) { offs[i] = a; cur[i] = a; a += cnt[i]; }
    offs[8] = a;
  }
}

__global__ void scatter_perm(const int* __restrict__ eidx, int* __restrict__ cur,
                             int* __restrict__ perm) {
  int t = blockIdx.x * blockDim.x + threadIdx.x;
  if (t < N_TOK) {
    int p = atomicAdd(&cur[eidx[t]], 1);
    perm[p] = t;
  }
}

// -------- expert GEMM: out = a_e*(x @ W[e] + b[e]); fused epilogue --------
// gathered A rows via perm; B = W^T f16 hi/lo [1024][1024]; BM=128 BN=64 BK=32
// depth-2 pipeline: 3 LDS buffers, counted vmcnt, raw barriers.
// SPLIT=1 buffer (halves): Ah[0,4096) Al[4096,8192) Bh[8192,10240) Bl[10240,12288)
// SPLIT=0 buffer (halves): Ah[0,4096) Bh[4096,6144)
template <int SPLIT>
__global__ __launch_bounds__(256, 2) void expert_gemm(
    const half_t* __restrict__ xh, const half_t* __restrict__ xl,
    const half_t* __restrict__ Wth, const half_t* __restrict__ Wtl,
    const float* __restrict__ bb, const float* __restrict__ asg,
    const int* __restrict__ perm, const int* __restrict__ offs,
    const float* __restrict__ hwp, const int lvl,
    float* __restrict__ dout, half_t* __restrict__ xnh, half_t* __restrict__ xnl) {
  constexpr int BUF = SPLIT ? 12288 : 6144;
  constexpr int OBH = SPLIT ? 8192 : 4096;
  __shared__ __align__(16) half_t lds[3 * BUF];
  __shared__ int toks[128];
  const int tid = threadIdx.x;
  int e = -1, base = 0, nrows = 0, acc_t = 0;
#pragma unroll
  for (int i = 0; i < 8; ++i) {
    int s = offs[i], t2 = offs[i + 1];
    int ntl = (t2 - s + 127) >> 7;
    if (e < 0 && (int)blockIdx.x < acc_t + ntl) {
      e = i;
      base = s + ((int)blockIdx.x - acc_t) * 128;
      nrows = t2 - base;
      if (nrows > 128) nrows = 128;
    }
    acc_t += ntl;
  }
  if (e < 0) return;
  if (tid < 128) toks[tid] = (tid < nrows) ? perm[base + tid] : perm[base];
  __syncthreads();
  const int srow = tid >> 2, skc = (tid & 3) * 8;
  const int tokA0 = toks[srow];
  const int tokA1 = toks[64 + srow];
  const half_t* gAh0 = xh + (size_t)tokA0 * H_DIM + skc;
  const half_t* gAh1 = xh + (size_t)tokA1 * H_DIM + skc;
  const half_t* gAl0 = SPLIT ? (xl + (size_t)tokA0 * H_DIM + skc) : nullptr;
  const half_t* gAl1 = SPLIT ? (xl + (size_t)tokA1 * H_DIM + skc) : nullptr;
  const size_t boffg = (size_t)e * H_DIM * H_DIM + (size_t)(blockIdx.y * 64 + srow) * H_DIM + skc;
  const half_t* gBh = Wth + boffg;
  const half_t* gBl = SPLIT ? (Wtl + boffg) : nullptr;

  f32x4 accM[4][2], accX[4][2];
#pragma unroll
  for (int m = 0; m < 4; ++m)
#pragma unroll
    for (int n = 0; n < 2; ++n) {
      accM[m][n] = {0.f, 0.f, 0.f, 0.f};
      accX[m][n] = {0.f, 0.f, 0.f, 0.f};
    }

  const int lane = tid & 63, wv = tid >> 6, wm = wv >> 1, wn = wv & 1;
  const int fr = lane & 15, fg = lane >> 4;
  const int aoff = (wm * 64 + fr) * 32 + fg * 8;
  const int boff = OBH + (wn * 32 + fr) * 32 + fg * 8;

#define E_STAGE(bo, kk) do { \
    const int go_ = (kk) * 32; \
    gload_lds16(gAh0 + go_, lds + (bo) + tid * 8); \
    gload_lds16(gAh1 + go_, lds + (bo) + 2048 + tid * 8); \
    gload_lds16(gBh + go_, lds + (bo) + OBH + tid * 8); \
    if (SPLIT) { \
      gload_lds16(gAl0 + go_, lds + (bo) + 4096 + tid * 8); \
      gload_lds16(gAl1 + go_, lds + (bo) + 4096 + 2048 + tid * 8); \
      gload_lds16(gBl + go_, lds + (bo) + 10240 + tid * 8); \
    } \
  } while (0)

  E_STAGE(0, 0);
  E_STAGE(BUF, 1);
  int cur = 0;
  for (int k = 0; k < 32; ++k) {
    if (k < 31) { if (SPLIT) { WAITV6; } else { WAITV3; } } else { WAITV0; }
    SCHEDB;
    RAWBAR;
    SCHEDB;
    if (k + 2 < 32) {
      int nxt = cur + 2; if (nxt >= 3) nxt -= 3;
      E_STAGE(nxt * BUF, k + 2);
    }
    const int cb = cur * BUF;
    half8 a_h[4], b_h[2], a_l[4], b_l[2];
#pragma unroll
    for (int m = 0; m < 4; ++m) {
      a_h[m] = *(const half8*)&lds[cb + aoff + m * 16 * 32];
      if (SPLIT) a_l[m] = *(const half8*)&lds[cb + 4096 + aoff + m * 16 * 32];
    }
#pragma unroll
    for (int n = 0; n < 2; ++n) {
      b_h[n] = *(const half8*)&lds[cb + boff + n * 16 * 32];
      if (SPLIT) b_l[n] = *(const half8*)&lds[cb + 2048 + boff + n * 16 * 32];
    }
#pragma unroll
    for (int m = 0; m < 4; ++m)
#pragma unroll
      for (int n = 0; n < 2; ++n) {
        accM[m][n] = __builtin_amdgcn_mfma_f32_16x16x32_f16(a_h[m], b_h[n], accM[m][n], 0, 0, 0);
        if (SPLIT) {
          accX[m][n] = __builtin_amdgcn_mfma_f32_16x16x32_f16(a_h[m], b_l[n], accX[m][n], 0, 0, 0);
          accX[m][n] = __builtin_amdgcn_mfma_f32_16x16x32_f16(a_l[m], b_h[n], accX[m][n], 0, 0, 0);
        }
      }
    SCHEDB;
    cur = (cur == 2) ? 0 : cur + 1;
  }
#undef E_STAGE

  const float ae = asg[e];
  const float hwv = hwp[lvl];
  const float inv = 1.0f / 2048.0f;
  const bool first = (lvl == 0);
#pragma unroll
  for (int m = 0; m < 4; ++m) {
    const int rl0 = wm * 64 + m * 16 + fg * 4;
#pragma unroll
    for (int n = 0; n < 2; ++n) {
      const int col = blockIdx.y * 64 + wn * 32 + n * 16 + fr;
      const float bbv = bb[(size_t)e * H_DIM + col];
#pragma unroll
      for (int r = 0; r < 4; ++r) {
        const int rl = rl0 + r;
        if (rl < nrows) {
          const int tok = toks[rl];
          float s = accM[m][n][r] + bbv;
          if (SPLIT) s += accX[m][n][r] * inv;
          const float o = ae * s;
          const size_t idx = (size_t)tok * H_DIM + col;
          const float fo = hwv * o;
          if (first) dout[idx] = fo; else dout[idx] += fo;
          if (SPLIT) {
            half_t hv = (half_t)o;
            xnh[idx] = hv;
            xnl[idx] = (half_t)((o - (float)hv) * 2048.f);
          }
        }
      }
    }
  }
}

extern "C" void kernel_launch(void* const* d_in, const int* in_sizes, int n_in,
                              void* d_out, int out_size, void* d_ws, size_t ws_size,
                              hipStream_t stream) {
  const float* hs  = (const float*)d_in[0];   // (2,4096,1024)
  const float* w1  = (const float*)d_in[1];   // (3,1024,512)
  const float* b1  = (const float*)d_in[2];   // (3,512)
  const float* w2  = (const float*)d_in[3];   // (3,512,8)
  const float* b2  = (const float*)d_in[4];   // (3,8)
  const float* lea = (const float*)d_in[5];   // (3,8)
  const float* hww = (const float*)d_in[6];   // (3,)
  const float* Wb  = (const float*)d_in[7];   // (3,8,1024,1024)
  const float* bb  = (const float*)d_in[8];   // (3,8,1024)
  float* outp = (float*)d_out;

  char* ws = (char*)d_ws;
  size_t off = 0;
  half_t* Wth  = (half_t*)(ws + off); off += (size_t)NE * H_DIM * H_DIM * 2;   // per-level, reused
  half_t* Wtl  = (half_t*)(ws + off); off += (size_t)NE * H_DIM * H_DIM * 2;
  half_t* w1th = (half_t*)(ws + off); off += (size_t)NL * D_DIM * H_DIM * 2;
  half_t* w1tl = (half_t*)(ws + off); off += (size_t)NL * D_DIM * H_DIM * 2;
  half_t* xh0  = (half_t*)(ws + off); off += (size_t)N_TOK * H_DIM * 2;
  half_t* xl0  = (half_t*)(ws + off); off += (size_t)N_TOK * H_DIM * 2;
  half_t* xh1  = (half_t*)(ws + off); off += (size_t)N_TOK * H_DIM * 2;
  half_t* xl1  = (half_t*)(ws + off); off += (size_t)N_TOK * H_DIM * 2;
  float*  hbuf = (float*)(ws + off);  off += (size_t)N_TOK * D_DIM * 4;
  int*    eidx = (int*)(ws + off);    off += (size_t)N_TOK * 4;
  int*    perm = (int*)(ws + off);    off += (size_t)N_TOK * 4;
  int*    cnt  = (int*)(ws + off);    off += (size_t)NL * NE * 4;
  int*    offs = (int*)(ws + off);    off += (size_t)NL * (NE + 1) * 4;
  int*    cur  = (int*)(ws + off);    off += (size_t)NL * NE * 4;
  float*  hwp  = (float*)(ws + off);  off += 16;

  init_small<<<1, 64, 0, stream>>>(hww, hwp, cnt);
  transpose_cvt<<<dim3(16, 8, NL), 256, 0, stream>>>(
      w1, (unsigned long long)H_DIM * D_DIM, w1th, w1tl,
      (unsigned long long)D_DIM * H_DIM, H_DIM, D_DIM);
  cvt_x_hilo<<<(N_TOK * H_DIM / 4 + 255) / 256, 256, 0, stream>>>(
      hs, xh0, xl0, N_TOK * H_DIM / 4);

  for (int l = 0; l < NL; ++l) {
    const half_t* xch = (l & 1) ? xh1 : xh0;
    const half_t* xcl = (l & 1) ? xl1 : xl0;
    half_t* xnh = (l == 2) ? (half_t*)nullptr : ((l & 1) ? xh0 : xh1);
    half_t* xnl = (l == 2) ? (half_t*)nullptr : ((l & 1) ? xl0 : xl1);
    // convert this level's W_base (hi always; lo only when split needed)
    transpose_cvt<<<dim3(16, 16, NE), 256, 0, stream>>>(
        Wb + (size_t)l * NE * H_DIM * H_DIM, (unsigned long long)H_DIM * H_DIM,
        Wth, (l < 2) ? Wtl : (half_t*)nullptr,
        (unsigned long long)H_DIM * H_DIM, H_DIM, H_DIM);
    routing_gemm<<<dim3(64, 8), 256, 0, stream>>>(
        xch, xcl, w1th + (size_t)l * D_DIM * H_DIM, w1tl + (size_t)l * D_DIM * H_DIM,
        b1 + l * D_DIM, hbuf);
    logits_argmax<<<N_TOK / 4, 256, 0, stream>>>(
        hbuf, w2 + (size_t)l * D_DIM * NE, b2 + l * NE, eidx, cnt + l * NE);
    scan8<<<1, 64, 0, stream>>>(cnt + l * NE, offs + l * (NE + 1), cur + l * NE);
    scatter_perm<<<N_TOK / 256, 256, 0, stream>>>(eidx, cur + l * NE, perm);
    if (l < 2) {
      expert_gemm<1><<<dim3(72, 16), 256, 0, stream>>>(
          xch, xcl, Wth, Wtl, bb + (size_t)l * NE * H_DIM,
          lea + l * NE, perm, offs + l * (NE + 1), hwp, l, outp, xnh, xnl);
    } else {
      expert_gemm<0><<<dim3(72, 16), 256, 0, stream>>>(
          xch, (const half_t*)nullptr, Wth, (const half_t*)nullptr,
          bb + (size_t)l * NE * H_DIM,
          lea + l * NE, perm, offs + l * (NE + 1), hwp, l, outp,
          (half_t*)nullptr, (half_t*)nullptr);
    }
  }
}

// Round 6
// 886.230 us; speedup vs baseline: 1.0573x; 1.0573x over previous
//
#include <hip/hip_runtime.h>
#include <stdint.h>

typedef _Float16 half_t;
typedef __attribute__((ext_vector_type(4))) _Float16 half4;
typedef __attribute__((ext_vector_type(8))) _Float16 half8;
typedef __attribute__((ext_vector_type(4))) float f32x4;

#define N_TOK 8192
#define H_DIM 1024
#define D_DIM 512
#define NE 8
#define NL 3

#define WAITV6 asm volatile("s_waitcnt vmcnt(6)" ::: "memory")
#define WAITV3 asm volatile("s_waitcnt vmcnt(3)" ::: "memory")
#define WAITV0 asm volatile("s_waitcnt vmcnt(0)" ::: "memory")
#define SCHEDB __builtin_amdgcn_sched_barrier(0)
#define RAWBAR __builtin_amdgcn_s_barrier()

// -------- async global->LDS, 16B per lane, linear dest --------
__device__ __forceinline__ void gload_lds16(const half_t* g, half_t* l) {
  __builtin_amdgcn_global_load_lds(
      (const __attribute__((address_space(1))) unsigned int*)g,
      (__attribute__((address_space(3))) unsigned int*)l, 16, 0, 0);
}

// Swizzle: LDS physical 16B-chunk p holds logical chunk c = p ^ (row&3) ^ ((row>>2)&3).
// Staging keeps LDS linear and permutes the per-lane GLOBAL chunk (rule #21);
// reads permute fg. Makes every 8-lane LDS phase hit 8 distinct 16B slots.

// -------- init: softmax over hierarchical weights + zero counters --------
__global__ void init_small(const float* __restrict__ w, float* __restrict__ hwp,
                           int* __restrict__ cnt) {
  const int t = threadIdx.x;
  if (t < NL * NE) cnt[t] = 0;
  if (t == 0) {
    float m = fmaxf(fmaxf(w[0], w[1]), w[2]);
    float e0 = expf(w[0] - m), e1 = expf(w[1] - m), e2 = expf(w[2] - m);
    float s = e0 + e1 + e2;
    hwp[0] = e0 / s; hwp[1] = e1 / s; hwp[2] = e2 / s;
  }
}

// -------- fp32 [R][C] -> f16 transposed [C][R], optional scaled-lo output --------
__global__ void transpose_cvt(const float* __restrict__ in, unsigned long long in_zs,
                              half_t* __restrict__ oh, half_t* __restrict__ ol,
                              unsigned long long out_zs, int R, int C) {
  __shared__ float tile[64][65];
  const float* src = in + (size_t)blockIdx.z * in_zs;
  const int rt = blockIdx.x * 64;
  const int ct = blockIdx.y * 64;
  const int tid = threadIdx.x;
  const int r = tid >> 2, c0 = (tid & 3) * 16;
  const float* p = src + (size_t)(rt + r) * C + ct + c0;
#pragma unroll
  for (int q = 0; q < 4; ++q) {
    float4 v = *(const float4*)(p + q * 4);
    tile[r][c0 + q * 4 + 0] = v.x;
    tile[r][c0 + q * 4 + 1] = v.y;
    tile[r][c0 + q * 4 + 2] = v.z;
    tile[r][c0 + q * 4 + 3] = v.w;
  }
  __syncthreads();
  const int nl = tid >> 2, k0 = (tid & 3) * 16;
  half8 hv0, hv1, lv0, lv1;
#pragma unroll
  for (int i = 0; i < 16; ++i) {
    float v = tile[k0 + i][nl];
    half_t h = (half_t)v;
    half_t lo = (half_t)((v - (float)h) * 2048.f);
    if (i < 8) { hv0[i] = h; lv0[i] = lo; } else { hv1[i - 8] = h; lv1[i - 8] = lo; }
  }
  half_t* dst = oh + (size_t)blockIdx.z * out_zs + (size_t)(ct + nl) * R + rt + k0;
  *(half8*)dst = hv0;
  *(half8*)(dst + 8) = hv1;
  if (ol) {
    half_t* dstl = ol + (size_t)blockIdx.z * out_zs + (size_t)(ct + nl) * R + rt + k0;
    *(half8*)dstl = lv0;
    *(half8*)(dstl + 8) = lv1;
  }
}

// -------- fp32 x -> f16 hi + scaled lo --------
__global__ void cvt_x_hilo(const float* __restrict__ in, half_t* __restrict__ oh,
                           half_t* __restrict__ ol, int n4) {
  int i = blockIdx.x * blockDim.x + threadIdx.x;
  if (i < n4) {
    float4 v = ((const float4*)in)[i];
    float vv[4] = {v.x, v.y, v.z, v.w};
    half4 hv, lv;
#pragma unroll
    for (int j = 0; j < 4; ++j) {
      half_t h = (half_t)vv[j];
      hv[j] = h;
      lv[j] = (half_t)((vv[j] - (float)h) * 2048.f);
    }
    ((half4*)oh)[i] = hv;
    ((half4*)ol)[i] = lv;
  }
}

// -------- router GEMM: h = relu(x @ w1 + b1), fp16-split 3-pass MFMA --------
// BM=128 BN=64 BK=32; 2 LDS buffers, counted vmcnt(6), raw barriers, swizzled LDS.
// buffer layout (elements): Ah[0,4096) Al[4096,8192) Bh[8192,10240) Bl[10240,12288)
__global__ __launch_bounds__(256, 3) void routing_gemm(
    const half_t* __restrict__ xh, const half_t* __restrict__ xl,
    const half_t* __restrict__ wh, const half_t* __restrict__ wl,
    const float* __restrict__ b1, float* __restrict__ hout) {
  __shared__ __align__(16) half_t lds[2 * 12288];
  const int tid = threadIdx.x;
  const int lane = tid & 63;
  const int wv = tid >> 6;
  const int wm = wv >> 1, wn = wv & 1;
  const int mt = blockIdx.x, nt = blockIdx.y;

  const int srow = tid >> 2;
  const int skc = (((tid & 3) ^ ((tid >> 2) & 3) ^ ((tid >> 4) & 3)) * 8);
  const half_t* gAh = xh + (size_t)(mt * 128 + srow) * H_DIM + skc;
  const half_t* gAl = xl + (size_t)(mt * 128 + srow) * H_DIM + skc;
  const half_t* gBh = wh + (size_t)(nt * 64 + srow) * H_DIM + skc;
  const half_t* gBl = wl + (size_t)(nt * 64 + srow) * H_DIM + skc;
  const size_t half_stride = (size_t)64 * H_DIM;

  f32x4 accM[4][2], accX[4][2];
#pragma unroll
  for (int m = 0; m < 4; ++m)
#pragma unroll
    for (int n = 0; n < 2; ++n) {
      accM[m][n] = {0.f, 0.f, 0.f, 0.f};
      accX[m][n] = {0.f, 0.f, 0.f, 0.f};
    }

  const int fr = lane & 15, fg = lane >> 4;
  const int fgs = fg ^ ((fr & 3) ^ ((fr >> 2) & 3));
  const int aoff = (wm * 64 + fr) * 32 + fgs * 8;
  const int boff = 8192 + (wn * 32 + fr) * 32 + fgs * 8;

#define R_STAGE(bo, kk) do { \
    const int go_ = (kk) * 32; \
    gload_lds16(gAh + go_, lds + (bo) + tid * 8); \
    gload_lds16(gAh + go_ + half_stride, lds + (bo) + 2048 + tid * 8); \
    gload_lds16(gAl + go_, lds + (bo) + 4096 + tid * 8); \
    gload_lds16(gAl + go_ + half_stride, lds + (bo) + 4096 + 2048 + tid * 8); \
    gload_lds16(gBh + go_, lds + (bo) + 8192 + tid * 8); \
    gload_lds16(gBl + go_, lds + (bo) + 10240 + tid * 8); \
  } while (0)

  R_STAGE(0, 0);
  for (int k = 0; k < 32; ++k) {
    if (k + 1 < 32) R_STAGE(((k + 1) & 1) * 12288, k + 1);
    if (k < 31) { WAITV6; } else { WAITV0; }
    SCHEDB;
    RAWBAR;
    SCHEDB;
    const int cb = (k & 1) * 12288;
    half8 a_h[4], a_l[4], b_h[2], b_l[2];
#pragma unroll
    for (int m = 0; m < 4; ++m) {
      a_h[m] = *(const half8*)&lds[cb + aoff + m * 512];
      a_l[m] = *(const half8*)&lds[cb + 4096 + aoff + m * 512];
    }
#pragma unroll
    for (int n = 0; n < 2; ++n) {
      b_h[n] = *(const half8*)&lds[cb + boff + n * 512];
      b_l[n] = *(const half8*)&lds[cb + 2048 + boff + n * 512];
    }
    __builtin_amdgcn_s_setprio(1);
#pragma unroll
    for (int m = 0; m < 4; ++m)
#pragma unroll
      for (int n = 0; n < 2; ++n) {
        accM[m][n] = __builtin_amdgcn_mfma_f32_16x16x32_f16(a_h[m], b_h[n], accM[m][n], 0, 0, 0);
        accX[m][n] = __builtin_amdgcn_mfma_f32_16x16x32_f16(a_h[m], b_l[n], accX[m][n], 0, 0, 0);
        accX[m][n] = __builtin_amdgcn_mfma_f32_16x16x32_f16(a_l[m], b_h[n], accX[m][n], 0, 0, 0);
      }
    __builtin_amdgcn_s_setprio(0);
    SCHEDB;
    RAWBAR;
    SCHEDB;
  }
#undef R_STAGE

  const float inv = 1.0f / 2048.0f;
#pragma unroll
  for (int m = 0; m < 4; ++m) {
    const int row0 = mt * 128 + wm * 64 + m * 16 + fg * 4;
#pragma unroll
    for (int n = 0; n < 2; ++n) {
      const int col = nt * 64 + wn * 32 + n * 16 + fr;
      const float bv = b1[col];
#pragma unroll
      for (int r = 0; r < 4; ++r) {
        float v = accM[m][n][r] + accX[m][n][r] * inv + bv;
        hout[(size_t)(row0 + r) * D_DIM + col] = fmaxf(v, 0.f);
      }
    }
  }
}

// -------- logits + argmax + per-expert count; one wave per token --------
__global__ void logits_argmax(const float* __restrict__ hbuf, const float* __restrict__ w2,
                              const float* __restrict__ b2, int* __restrict__ eidx,
                              int* __restrict__ cnt) {
  const int tid = threadIdx.x, lane = tid & 63, wv = tid >> 6;
  const int t = blockIdx.x * 4 + wv;
  const float* hr = hbuf + (size_t)t * D_DIM;
  float4 h0 = *(const float4*)(hr + lane * 8);
  float4 h1 = *(const float4*)(hr + lane * 8 + 4);
  float p[8] = {0, 0, 0, 0, 0, 0, 0, 0};
  const float* wr = w2 + (size_t)lane * 8 * 8;
  float hv[8] = {h0.x, h0.y, h0.z, h0.w, h1.x, h1.y, h1.z, h1.w};
#pragma unroll
  for (int j = 0; j < 8; ++j) {
    float4 wa = *(const float4*)(wr + j * 8);
    float4 wb = *(const float4*)(wr + j * 8 + 4);
    p[0] += hv[j] * wa.x; p[1] += hv[j] * wa.y; p[2] += hv[j] * wa.z; p[3] += hv[j] * wa.w;
    p[4] += hv[j] * wb.x; p[5] += hv[j] * wb.y; p[6] += hv[j] * wb.z; p[7] += hv[j] * wb.w;
  }
#pragma unroll
  for (int o = 32; o > 0; o >>= 1) {
#pragma unroll
    for (int e = 0; e < 8; ++e) p[e] += __shfl_xor(p[e], o, 64);
  }
  if (lane == 0) {
    int best = 0;
    float bvv = p[0] + b2[0];
#pragma unroll
    for (int e = 1; e < 8; ++e) {
      float v = p[e] + b2[e];
      if (v > bvv) { bvv = v; best = e; }
    }
    eidx[t] = best;
    atomicAdd(&cnt[best], 1);
  }
}

__global__ void scan8(const int* __restrict__ cnt, int* __restrict__ offs, int* __restrict__ cur) {
  if (threadIdx.x == 0) {
    int a = 0;
    for (int i = 0; i < 8; ++i) { offs[i] = a; cur[i] = a; a += cnt[i]; }
    offs[8] = a;
  }
}

__global__ void scatter_perm(const int* __restrict__ eidx, int* __restrict__ cur,
                             int* __restrict__ perm) {
  int t = blockIdx.x * blockDim.x + threadIdx.x;
  if (t < N_TOK) {
    int p = atomicAdd(&cur[eidx[t]], 1);
    perm[p] = t;
  }
}

// -------- expert GEMM: out = a_e*(x @ W[e] + b[e]); fused epilogue --------
// BM=128 BN=64 BK=32; 2 LDS buffers, counted vmcnt, raw barriers, swizzled LDS.
// SPLIT=1 buffer: Ah[0,4096) Al[4096,8192) Bh[8192,10240) Bl[10240,12288)
// SPLIT=0 buffer: Ah[0,4096) Bh[4096,6144)
template <int SPLIT>
__global__ __launch_bounds__(256, 3) void expert_gemm(
    const half_t* __restrict__ xh, const half_t* __restrict__ xl,
    const half_t* __restrict__ Wth, const half_t* __restrict__ Wtl,
    const float* __restrict__ bb, const float* __restrict__ asg,
    const int* __restrict__ perm, const int* __restrict__ offs,
    const float* __restrict__ hwp, const int lvl,
    float* __restrict__ dout, half_t* __restrict__ xnh, half_t* __restrict__ xnl) {
  constexpr int BUF = SPLIT ? 12288 : 6144;
  constexpr int OBH = SPLIT ? 8192 : 4096;
  __shared__ __align__(16) half_t lds[2 * BUF];
  __shared__ int toks[128];
  const int tid = threadIdx.x;
  int e = -1, base = 0, nrows = 0, acc_t = 0;
#pragma unroll
  for (int i = 0; i < 8; ++i) {
    int s = offs[i], t2 = offs[i + 1];
    int ntl = (t2 - s + 127) >> 7;
    if (e < 0 && (int)blockIdx.x < acc_t + ntl) {
      e = i;
      base = s + ((int)blockIdx.x - acc_t) * 128;
      nrows = t2 - base;
      if (nrows > 128) nrows = 128;
    }
    acc_t += ntl;
  }
  if (e < 0) return;
  if (tid < 128) toks[tid] = (tid < nrows) ? perm[base + tid] : perm[base];
  __syncthreads();
  const int srow = tid >> 2;
  const int skc = (((tid & 3) ^ ((tid >> 2) & 3) ^ ((tid >> 4) & 3)) * 8);
  const int tokA0 = toks[srow];
  const int tokA1 = toks[64 + srow];
  const half_t* gAh0 = xh + (size_t)tokA0 * H_DIM + skc;
  const half_t* gAh1 = xh + (size_t)tokA1 * H_DIM + skc;
  const half_t* gAl0 = SPLIT ? (xl + (size_t)tokA0 * H_DIM + skc) : nullptr;
  const half_t* gAl1 = SPLIT ? (xl + (size_t)tokA1 * H_DIM + skc) : nullptr;
  const size_t boffg = (size_t)e * H_DIM * H_DIM + (size_t)(blockIdx.y * 64 + srow) * H_DIM + skc;
  const half_t* gBh = Wth + boffg;
  const half_t* gBl = SPLIT ? (Wtl + boffg) : nullptr;

  f32x4 accM[4][2], accX[4][2];
#pragma unroll
  for (int m = 0; m < 4; ++m)
#pragma unroll
    for (int n = 0; n < 2; ++n) {
      accM[m][n] = {0.f, 0.f, 0.f, 0.f};
      accX[m][n] = {0.f, 0.f, 0.f, 0.f};
    }

  const int lane = tid & 63, wv = tid >> 6, wm = wv >> 1, wn = wv & 1;
  const int fr = lane & 15, fg = lane >> 4;
  const int fgs = fg ^ ((fr & 3) ^ ((fr >> 2) & 3));
  const int aoff = (wm * 64 + fr) * 32 + fgs * 8;
  const int boff = OBH + (wn * 32 + fr) * 32 + fgs * 8;

#define E_STAGE(bo, kk) do { \
    const int go_ = (kk) * 32; \
    gload_lds16(gAh0 + go_, lds + (bo) + tid * 8); \
    gload_lds16(gAh1 + go_, lds + (bo) + 2048 + tid * 8); \
    gload_lds16(gBh + go_, lds + (bo) + OBH + tid * 8); \
    if (SPLIT) { \
      gload_lds16(gAl0 + go_, lds + (bo) + 4096 + tid * 8); \
      gload_lds16(gAl1 + go_, lds + (bo) + 4096 + 2048 + tid * 8); \
      gload_lds16(gBl + go_, lds + (bo) + 10240 + tid * 8); \
    } \
  } while (0)

  E_STAGE(0, 0);
  for (int k = 0; k < 32; ++k) {
    if (k + 1 < 32) E_STAGE(((k + 1) & 1) * BUF, k + 1);
    if (k < 31) { if (SPLIT) { WAITV6; } else { WAITV3; } } else { WAITV0; }
    SCHEDB;
    RAWBAR;
    SCHEDB;
    const int cb = (k & 1) * BUF;
    half8 a_h[4], b_h[2], a_l[4], b_l[2];
#pragma unroll
    for (int m = 0; m < 4; ++m) {
      a_h[m] = *(const half8*)&lds[cb + aoff + m * 512];
      if (SPLIT) a_l[m] = *(const half8*)&lds[cb + 4096 + aoff + m * 512];
    }
#pragma unroll
    for (int n = 0; n < 2; ++n) {
      b_h[n] = *(const half8*)&lds[cb + boff + n * 512];
      if (SPLIT) b_l[n] = *(const half8*)&lds[cb + 2048 + boff + n * 512];
    }
    __builtin_amdgcn_s_setprio(1);
#pragma unroll
    for (int m = 0; m < 4; ++m)
#pragma unroll
      for (int n = 0; n < 2; ++n) {
        accM[m][n] = __builtin_amdgcn_mfma_f32_16x16x32_f16(a_h[m], b_h[n], accM[m][n], 0, 0, 0);
        if (SPLIT) {
          accX[m][n] = __builtin_amdgcn_mfma_f32_16x16x32_f16(a_h[m], b_l[n], accX[m][n], 0, 0, 0);
          accX[m][n] = __builtin_amdgcn_mfma_f32_16x16x32_f16(a_l[m], b_h[n], accX[m][n], 0, 0, 0);
        }
      }
    __builtin_amdgcn_s_setprio(0);
    SCHEDB;
    RAWBAR;
    SCHEDB;
  }
#undef E_STAGE

  const float ae = asg[e];
  const float hwv = hwp[lvl];
  const float inv = 1.0f / 2048.0f;
  const bool first = (lvl == 0);
#pragma unroll
  for (int m = 0; m < 4; ++m) {
    const int rl0 = wm * 64 + m * 16 + fg * 4;
#pragma unroll
    for (int n = 0; n < 2; ++n) {
      const int col = blockIdx.y * 64 + wn * 32 + n * 16 + fr;
      const float bbv = bb[(size_t)e * H_DIM + col];
#pragma unroll
      for (int r = 0; r < 4; ++r) {
        const int rl = rl0 + r;
        if (rl < nrows) {
          const int tok = toks[rl];
          float s = accM[m][n][r] + bbv;
          if (SPLIT) s += accX[m][n][r] * inv;
          const float o = ae * s;
          const size_t idx = (size_t)tok * H_DIM + col;
          const float fo = hwv * o;
          if (first) dout[idx] = fo; else dout[idx] += fo;
          if (SPLIT) {
            half_t hv = (half_t)o;
            xnh[idx] = hv;
            xnl[idx] = (half_t)((o - (float)hv) * 2048.f);
          }
        }
      }
    }
  }
}

extern "C" void kernel_launch(void* const* d_in, const int* in_sizes, int n_in,
                              void* d_out, int out_size, void* d_ws, size_t ws_size,
                              hipStream_t stream) {
  const float* hs  = (const float*)d_in[0];   // (2,4096,1024)
  const float* w1  = (const float*)d_in[1];   // (3,1024,512)
  const float* b1  = (const float*)d_in[2];   // (3,512)
  const float* w2  = (const float*)d_in[3];   // (3,512,8)
  const float* b2  = (const float*)d_in[4];   // (3,8)
  const float* lea = (const float*)d_in[5];   // (3,8)
  const float* hww = (const float*)d_in[6];   // (3,)
  const float* Wb  = (const float*)d_in[7];   // (3,8,1024,1024)
  const float* bb  = (const float*)d_in[8];   // (3,8,1024)
  float* outp = (float*)d_out;

  char* ws = (char*)d_ws;
  size_t off = 0;
  half_t* Wth  = (half_t*)(ws + off); off += (size_t)NE * H_DIM * H_DIM * 2;   // per-level, reused
  half_t* Wtl  = (half_t*)(ws + off); off += (size_t)NE * H_DIM * H_DIM * 2;
  half_t* w1th = (half_t*)(ws + off); off += (size_t)NL * D_DIM * H_DIM * 2;
  half_t* w1tl = (half_t*)(ws + off); off += (size_t)NL * D_DIM * H_DIM * 2;
  half_t* xh0  = (half_t*)(ws + off); off += (size_t)N_TOK * H_DIM * 2;
  half_t* xl0  = (half_t*)(ws + off); off += (size_t)N_TOK * H_DIM * 2;
  half_t* xh1  = (half_t*)(ws + off); off += (size_t)N_TOK * H_DIM * 2;
  half_t* xl1  = (half_t*)(ws + off); off += (size_t)N_TOK * H_DIM * 2;
  float*  hbuf = (float*)(ws + off);  off += (size_t)N_TOK * D_DIM * 4;
  int*    eidx = (int*)(ws + off);    off += (size_t)N_TOK * 4;
  int*    perm = (int*)(ws + off);    off += (size_t)N_TOK * 4;
  int*    cnt  = (int*)(ws + off);    off += (size_t)NL * NE * 4;
  int*    offs = (int*)(ws + off);    off += (size_t)NL * (NE + 1) * 4;
  int*    cur  = (int*)(ws + off);    off += (size_t)NL * NE * 4;
  float*  hwp  = (float*)(ws + off);  off += 16;

  init_small<<<1, 64, 0, stream>>>(hww, hwp, cnt);
  transpose_cvt<<<dim3(16, 8, NL), 256, 0, stream>>>(
      w1, (unsigned long long)H_DIM * D_DIM, w1th, w1tl,
      (unsigned long long)D_DIM * H_DIM, H_DIM, D_DIM);
  cvt_x_hilo<<<(N_TOK * H_DIM / 4 + 255) / 256, 256, 0, stream>>>(
      hs, xh0, xl0, N_TOK * H_DIM / 4);

  for (int l = 0; l < NL; ++l) {
    const half_t* xch = (l & 1) ? xh1 : xh0;
    const half_t* xcl = (l & 1) ? xl1 : xl0;
    half_t* xnh = (l == 2) ? (half_t*)nullptr : ((l & 1) ? xh0 : xh1);
    half_t* xnl = (l == 2) ? (half_t*)nullptr : ((l & 1) ? xl0 : xl1);
    // convert this level's W_base (hi always; lo only when split needed)
    transpose_cvt<<<dim3(16, 16, NE), 256, 0, stream>>>(
        Wb + (size_t)l * NE * H_DIM * H_DIM, (unsigned long long)H_DIM * H_DIM,
        Wth, (l < 2) ? Wtl : (half_t*)nullptr,
        (unsigned long long)H_DIM * H_DIM, H_DIM, H_DIM);
    routing_gemm<<<dim3(64, 8), 256, 0, stream>>>(
        xch, xcl, w1th + (size_t)l * D_DIM * H_DIM, w1tl + (size_t)l * D_DIM * H_DIM,
        b1 + l * D_DIM, hbuf);
    logits_argmax<<<N_TOK / 4, 256, 0, stream>>>(
        hbuf, w2 + (size_t)l * D_DIM * NE, b2 + l * NE, eidx, cnt + l * NE);
    scan8<<<1, 64, 0, stream>>>(cnt + l * NE, offs + l * (NE + 1), cur + l * NE);
    scatter_perm<<<N_TOK / 256, 256, 0, stream>>>(eidx, cur + l * NE, perm);
    if (l < 2) {
      expert_gemm<1><<<dim3(72, 16), 256, 0, stream>>>(
          xch, xcl, Wth, Wtl, bb + (size_t)l * NE * H_DIM,
          lea + l * NE, perm, offs + l * (NE + 1), hwp, l, outp, xnh, xnl);
    } else {
      expert_gemm<0><<<dim3(72, 16), 256, 0, stream>>>(
          xch, (const half_t*)nullptr, Wth, (const half_t*)nullptr,
          bb + (size_t)l * NE * H_DIM,
          lea + l * NE, perm, offs + l * (NE + 1), hwp, l, outp,
          (half_t*)nullptr, (half_t*)nullptr);
    }
  }
}

// Round 7
// 871.422 us; speedup vs baseline: 1.0753x; 1.0170x over previous
//
#include <hip/hip_runtime.h>
#include <stdint.h>

typedef _Float16 half_t;
typedef __attribute__((ext_vector_type(4))) _Float16 half4;
typedef __attribute__((ext_vector_type(8))) _Float16 half8;
typedef __attribute__((ext_vector_type(4))) float f32x4;

#define N_TOK 8192
#define H_DIM 1024
#define D_DIM 512
#define NE 8
#define NL 3

#define WAITV6 asm volatile("s_waitcnt vmcnt(6)" ::: "memory")
#define WAITV3 asm volatile("s_waitcnt vmcnt(3)" ::: "memory")
#define WAITV0 asm volatile("s_waitcnt vmcnt(0)" ::: "memory")
#define SCHEDB __builtin_amdgcn_sched_barrier(0)
#define RAWBAR __builtin_amdgcn_s_barrier()

// -------- async global->LDS, 16B per lane, linear dest --------
__device__ __forceinline__ void gload_lds16(const half_t* g, half_t* l) {
  __builtin_amdgcn_global_load_lds(
      (const __attribute__((address_space(1))) unsigned int*)g,
      (__attribute__((address_space(3))) unsigned int*)l, 16, 0, 0);
}

// -------- init: softmax over hierarchical weights + zero counters --------
__global__ void init_small(const float* __restrict__ w, float* __restrict__ hwp,
                           int* __restrict__ cnt, int* __restrict__ done) {
  const int t = threadIdx.x;
  if (t < NL * NE) cnt[t] = 0;
  if (t < NL) done[t] = 0;
  if (t == 0) {
    float m = fmaxf(fmaxf(w[0], w[1]), w[2]);
    float e0 = expf(w[0] - m), e1 = expf(w[1] - m), e2 = expf(w[2] - m);
    float s = e0 + e1 + e2;
    hwp[0] = e0 / s; hwp[1] = e1 / s; hwp[2] = e2 / s;
  }
}

// -------- fp32 [R][C] -> f16 transposed [C][R], optional scaled-lo output --------
__global__ void transpose_cvt(const float* __restrict__ in, unsigned long long in_zs,
                              half_t* __restrict__ oh, half_t* __restrict__ ol,
                              unsigned long long out_zs, int R, int C) {
  __shared__ float tile[64][65];
  const float* src = in + (size_t)blockIdx.z * in_zs;
  const int rt = blockIdx.x * 64;
  const int ct = blockIdx.y * 64;
  const int tid = threadIdx.x;
  const int r = tid >> 2, c0 = (tid & 3) * 16;
  const float* p = src + (size_t)(rt + r) * C + ct + c0;
#pragma unroll
  for (int q = 0; q < 4; ++q) {
    float4 v = *(const float4*)(p + q * 4);
    tile[r][c0 + q * 4 + 0] = v.x;
    tile[r][c0 + q * 4 + 1] = v.y;
    tile[r][c0 + q * 4 + 2] = v.z;
    tile[r][c0 + q * 4 + 3] = v.w;
  }
  __syncthreads();
  const int nl = tid >> 2, k0 = (tid & 3) * 16;
  half8 hv0, hv1, lv0, lv1;
#pragma unroll
  for (int i = 0; i < 16; ++i) {
    float v = tile[k0 + i][nl];
    half_t h = (half_t)v;
    half_t lo = (half_t)((v - (float)h) * 2048.f);
    if (i < 8) { hv0[i] = h; lv0[i] = lo; } else { hv1[i - 8] = h; lv1[i - 8] = lo; }
  }
  half_t* dst = oh + (size_t)blockIdx.z * out_zs + (size_t)(ct + nl) * R + rt + k0;
  *(half8*)dst = hv0;
  *(half8*)(dst + 8) = hv1;
  if (ol) {
    half_t* dstl = ol + (size_t)blockIdx.z * out_zs + (size_t)(ct + nl) * R + rt + k0;
    *(half8*)dstl = lv0;
    *(half8*)(dstl + 8) = lv1;
  }
}

// -------- fp32 x -> f16 hi + scaled lo --------
__global__ void cvt_x_hilo(const float* __restrict__ in, half_t* __restrict__ oh,
                           half_t* __restrict__ ol, int n4) {
  int i = blockIdx.x * blockDim.x + threadIdx.x;
  if (i < n4) {
    float4 v = ((const float4*)in)[i];
    float vv[4] = {v.x, v.y, v.z, v.w};
    half4 hv, lv;
#pragma unroll
    for (int j = 0; j < 4; ++j) {
      half_t h = (half_t)vv[j];
      hv[j] = h;
      lv[j] = (half_t)((vv[j] - (float)h) * 2048.f);
    }
    ((half4*)oh)[i] = hv;
    ((half4*)ol)[i] = lv;
  }
}

// -------- router GEMM: h = relu(x @ w1 + b1), fp16-split 3-pass MFMA --------
// BM=128 BN=64 BK=32; 1-D grid 512, XCD-chunked swizzle (64 Mtiles x 8 Ntiles).
__global__ __launch_bounds__(256, 3) void routing_gemm(
    const half_t* __restrict__ xh, const half_t* __restrict__ xl,
    const half_t* __restrict__ wh, const half_t* __restrict__ wl,
    const float* __restrict__ b1, float* __restrict__ hout) {
  __shared__ __align__(16) half_t lds[2 * 12288];
  const int tid = threadIdx.x;
  const int lane = tid & 63;
  const int wv = tid >> 6;
  const int wm = wv >> 1, wn = wv & 1;
  // XCD-chunked: each XCD gets 64 consecutive lids = 8 Mtiles x 8 Ntiles
  const int lid = ((int)blockIdx.x & 7) * 64 + ((int)blockIdx.x >> 3);
  const int nt = lid & 7, mt = lid >> 3;

  const int srow = tid >> 2;
  const int skc = (((tid & 3) ^ ((tid >> 2) & 3) ^ ((tid >> 4) & 3)) * 8);
  const half_t* gAh = xh + (size_t)(mt * 128 + srow) * H_DIM + skc;
  const half_t* gAl = xl + (size_t)(mt * 128 + srow) * H_DIM + skc;
  const half_t* gBh = wh + (size_t)(nt * 64 + srow) * H_DIM + skc;
  const half_t* gBl = wl + (size_t)(nt * 64 + srow) * H_DIM + skc;
  const size_t half_stride = (size_t)64 * H_DIM;

  f32x4 accM[4][2], accX[4][2];
#pragma unroll
  for (int m = 0; m < 4; ++m)
#pragma unroll
    for (int n = 0; n < 2; ++n) {
      accM[m][n] = {0.f, 0.f, 0.f, 0.f};
      accX[m][n] = {0.f, 0.f, 0.f, 0.f};
    }

  const int fr = lane & 15, fg = lane >> 4;
  const int fgs = fg ^ ((fr & 3) ^ ((fr >> 2) & 3));
  const int aoff = (wm * 64 + fr) * 32 + fgs * 8;
  const int boff = 8192 + (wn * 32 + fr) * 32 + fgs * 8;

#define R_STAGE(bo, kk) do { \
    const int go_ = (kk) * 32; \
    gload_lds16(gAh + go_, lds + (bo) + tid * 8); \
    gload_lds16(gAh + go_ + half_stride, lds + (bo) + 2048 + tid * 8); \
    gload_lds16(gAl + go_, lds + (bo) + 4096 + tid * 8); \
    gload_lds16(gAl + go_ + half_stride, lds + (bo) + 4096 + 2048 + tid * 8); \
    gload_lds16(gBh + go_, lds + (bo) + 8192 + tid * 8); \
    gload_lds16(gBl + go_, lds + (bo) + 10240 + tid * 8); \
  } while (0)

  R_STAGE(0, 0);
  for (int k = 0; k < 32; ++k) {
    if (k + 1 < 32) R_STAGE(((k + 1) & 1) * 12288, k + 1);
    if (k < 31) { WAITV6; } else { WAITV0; }
    SCHEDB;
    RAWBAR;
    SCHEDB;
    const int cb = (k & 1) * 12288;
    half8 a_h[4], a_l[4], b_h[2], b_l[2];
#pragma unroll
    for (int m = 0; m < 4; ++m) {
      a_h[m] = *(const half8*)&lds[cb + aoff + m * 512];
      a_l[m] = *(const half8*)&lds[cb + 4096 + aoff + m * 512];
    }
#pragma unroll
    for (int n = 0; n < 2; ++n) {
      b_h[n] = *(const half8*)&lds[cb + boff + n * 512];
      b_l[n] = *(const half8*)&lds[cb + 2048 + boff + n * 512];
    }
    __builtin_amdgcn_s_setprio(1);
#pragma unroll
    for (int m = 0; m < 4; ++m)
#pragma unroll
      for (int n = 0; n < 2; ++n) {
        accM[m][n] = __builtin_amdgcn_mfma_f32_16x16x32_f16(a_h[m], b_h[n], accM[m][n], 0, 0, 0);
        accX[m][n] = __builtin_amdgcn_mfma_f32_16x16x32_f16(a_h[m], b_l[n], accX[m][n], 0, 0, 0);
        accX[m][n] = __builtin_amdgcn_mfma_f32_16x16x32_f16(a_l[m], b_h[n], accX[m][n], 0, 0, 0);
      }
    __builtin_amdgcn_s_setprio(0);
    SCHEDB;
    RAWBAR;
    SCHEDB;
  }
#undef R_STAGE

  const float inv = 1.0f / 2048.0f;
#pragma unroll
  for (int m = 0; m < 4; ++m) {
    const int row0 = mt * 128 + wm * 64 + m * 16 + fg * 4;
#pragma unroll
    for (int n = 0; n < 2; ++n) {
      const int col = nt * 64 + wn * 32 + n * 16 + fr;
      const float bv = b1[col];
#pragma unroll
      for (int r = 0; r < 4; ++r) {
        float v = accM[m][n][r] + accX[m][n][r] * inv + bv;
        hout[(size_t)(row0 + r) * D_DIM + col] = fmaxf(v, 0.f);
      }
    }
  }
}

// -------- logits + argmax + per-expert count; one wave per token --------
// Last block (device-scope ticket) computes the 8-bin scan -> offs/cur.
__global__ void logits_argmax(const float* __restrict__ hbuf, const float* __restrict__ w2,
                              const float* __restrict__ b2, int* __restrict__ eidx,
                              int* __restrict__ cnt, int* __restrict__ done,
                              int* __restrict__ offs, int* __restrict__ cur) {
  const int tid = threadIdx.x, lane = tid & 63, wv = tid >> 6;
  const int t = blockIdx.x * 4 + wv;
  const float* hr = hbuf + (size_t)t * D_DIM;
  float4 h0 = *(const float4*)(hr + lane * 8);
  float4 h1 = *(const float4*)(hr + lane * 8 + 4);
  float p[8] = {0, 0, 0, 0, 0, 0, 0, 0};
  const float* wr = w2 + (size_t)lane * 8 * 8;
  float hv[8] = {h0.x, h0.y, h0.z, h0.w, h1.x, h1.y, h1.z, h1.w};
#pragma unroll
  for (int j = 0; j < 8; ++j) {
    float4 wa = *(const float4*)(wr + j * 8);
    float4 wb = *(const float4*)(wr + j * 8 + 4);
    p[0] += hv[j] * wa.x; p[1] += hv[j] * wa.y; p[2] += hv[j] * wa.z; p[3] += hv[j] * wa.w;
    p[4] += hv[j] * wb.x; p[5] += hv[j] * wb.y; p[6] += hv[j] * wb.z; p[7] += hv[j] * wb.w;
  }
#pragma unroll
  for (int o = 32; o > 0; o >>= 1) {
#pragma unroll
    for (int e = 0; e < 8; ++e) p[e] += __shfl_xor(p[e], o, 64);
  }
  if (lane == 0) {
    int best = 0;
    float bvv = p[0] + b2[0];
#pragma unroll
    for (int e = 1; e < 8; ++e) {
      float v = p[e] + b2[e];
      if (v > bvv) { bvv = v; best = e; }
    }
    eidx[t] = best;
    atomicAdd(&cnt[best], 1);
  }
  __syncthreads();
  if (tid == 0) {
    __threadfence();
    int tix = atomicAdd(done, 1);
    if (tix == (int)gridDim.x - 1) {
      int a = 0;
#pragma unroll
      for (int i = 0; i < 8; ++i) { offs[i] = a; cur[i] = a; a += cnt[i]; }
      offs[8] = a;
      __threadfence();
    }
  }
}

__global__ void scatter_perm(const int* __restrict__ eidx, int* __restrict__ cur,
                             int* __restrict__ perm) {
  int t = blockIdx.x * blockDim.x + threadIdx.x;
  if (t < N_TOK) {
    int p = atomicAdd(&cur[eidx[t]], 1);
    perm[p] = t;
  }
}

// -------- expert GEMM: out = a_e*(x @ W[e] + b[e]); fused epilogue --------
// BM=128 BN=64 BK=32; 1-D grid 1152, XCD-chunked (144 lids/XCD = 9 token-tiles x 16 N).
template <int SPLIT>
__global__ __launch_bounds__(256, 3) void expert_gemm(
    const half_t* __restrict__ xh, const half_t* __restrict__ xl,
    const half_t* __restrict__ Wth, const half_t* __restrict__ Wtl,
    const float* __restrict__ bb, const float* __restrict__ asg,
    const int* __restrict__ perm, const int* __restrict__ offs,
    const float* __restrict__ hwp, const int lvl,
    float* __restrict__ dout, half_t* __restrict__ xnh, half_t* __restrict__ xnl) {
  constexpr int BUF = SPLIT ? 12288 : 6144;
  constexpr int OBH = SPLIT ? 8192 : 4096;
  __shared__ __align__(16) half_t lds[2 * BUF];
  __shared__ int toks[128];
  const int tid = threadIdx.x;
  // XCD-chunked linear id: N-tile fastest within chunk -> A-panel reuse in-XCD
  const int lid = ((int)blockIdx.x & 7) * 144 + ((int)blockIdx.x >> 3);
  const int byn = lid & 15;   // N-tile 0..15
  const int bxt = lid >> 4;   // token-tile 0..71
  int e = -1, base = 0, nrows = 0, acc_t = 0;
#pragma unroll
  for (int i = 0; i < 8; ++i) {
    int s = offs[i], t2 = offs[i + 1];
    int ntl = (t2 - s + 127) >> 7;
    if (e < 0 && bxt < acc_t + ntl) {
      e = i;
      base = s + (bxt - acc_t) * 128;
      nrows = t2 - base;
      if (nrows > 128) nrows = 128;
    }
    acc_t += ntl;
  }
  if (e < 0) return;
  if (tid < 128) toks[tid] = (tid < nrows) ? perm[base + tid] : perm[base];
  __syncthreads();
  const int srow = tid >> 2;
  const int skc = (((tid & 3) ^ ((tid >> 2) & 3) ^ ((tid >> 4) & 3)) * 8);
  const int tokA0 = toks[srow];
  const int tokA1 = toks[64 + srow];
  const half_t* gAh0 = xh + (size_t)tokA0 * H_DIM + skc;
  const half_t* gAh1 = xh + (size_t)tokA1 * H_DIM + skc;
  const half_t* gAl0 = SPLIT ? (xl + (size_t)tokA0 * H_DIM + skc) : nullptr;
  const half_t* gAl1 = SPLIT ? (xl + (size_t)tokA1 * H_DIM + skc) : nullptr;
  const size_t boffg = (size_t)e * H_DIM * H_DIM + (size_t)(byn * 64 + srow) * H_DIM + skc;
  const half_t* gBh = Wth + boffg;
  const half_t* gBl = SPLIT ? (Wtl + boffg) : nullptr;

  f32x4 accM[4][2], accX[4][2];
#pragma unroll
  for (int m = 0; m < 4; ++m)
#pragma unroll
    for (int n = 0; n < 2; ++n) {
      accM[m][n] = {0.f, 0.f, 0.f, 0.f};
      accX[m][n] = {0.f, 0.f, 0.f, 0.f};
    }

  const int lane = tid & 63, wv = tid >> 6, wm = wv >> 1, wn = wv & 1;
  const int fr = lane & 15, fg = lane >> 4;
  const int fgs = fg ^ ((fr & 3) ^ ((fr >> 2) & 3));
  const int aoff = (wm * 64 + fr) * 32 + fgs * 8;
  const int boff = OBH + (wn * 32 + fr) * 32 + fgs * 8;

#define E_STAGE(bo, kk) do { \
    const int go_ = (kk) * 32; \
    gload_lds16(gAh0 + go_, lds + (bo) + tid * 8); \
    gload_lds16(gAh1 + go_, lds + (bo) + 2048 + tid * 8); \
    gload_lds16(gBh + go_, lds + (bo) + OBH + tid * 8); \
    if (SPLIT) { \
      gload_lds16(gAl0 + go_, lds + (bo) + 4096 + tid * 8); \
      gload_lds16(gAl1 + go_, lds + (bo) + 4096 + 2048 + tid * 8); \
      gload_lds16(gBl + go_, lds + (bo) + 10240 + tid * 8); \
    } \
  } while (0)

  E_STAGE(0, 0);
  for (int k = 0; k < 32; ++k) {
    if (k + 1 < 32) E_STAGE(((k + 1) & 1) * BUF, k + 1);
    if (k < 31) { if (SPLIT) { WAITV6; } else { WAITV3; } } else { WAITV0; }
    SCHEDB;
    RAWBAR;
    SCHEDB;
    const int cb = (k & 1) * BUF;
    half8 a_h[4], b_h[2], a_l[4], b_l[2];
#pragma unroll
    for (int m = 0; m < 4; ++m) {
      a_h[m] = *(const half8*)&lds[cb + aoff + m * 512];
      if (SPLIT) a_l[m] = *(const half8*)&lds[cb + 4096 + aoff + m * 512];
    }
#pragma unroll
    for (int n = 0; n < 2; ++n) {
      b_h[n] = *(const half8*)&lds[cb + boff + n * 512];
      if (SPLIT) b_l[n] = *(const half8*)&lds[cb + 2048 + boff + n * 512];
    }
    __builtin_amdgcn_s_setprio(1);
#pragma unroll
    for (int m = 0; m < 4; ++m)
#pragma unroll
      for (int n = 0; n < 2; ++n) {
        accM[m][n] = __builtin_amdgcn_mfma_f32_16x16x32_f16(a_h[m], b_h[n], accM[m][n], 0, 0, 0);
        if (SPLIT) {
          accX[m][n] = __builtin_amdgcn_mfma_f32_16x16x32_f16(a_h[m], b_l[n], accX[m][n], 0, 0, 0);
          accX[m][n] = __builtin_amdgcn_mfma_f32_16x16x32_f16(a_l[m], b_h[n], accX[m][n], 0, 0, 0);
        }
      }
    __builtin_amdgcn_s_setprio(0);
    SCHEDB;
    RAWBAR;
    SCHEDB;
  }
#undef E_STAGE

  const float ae = asg[e];
  const float hwv = hwp[lvl];
  const float inv = 1.0f / 2048.0f;
  const bool first = (lvl == 0);
#pragma unroll
  for (int m = 0; m < 4; ++m) {
    const int rl0 = wm * 64 + m * 16 + fg * 4;
#pragma unroll
    for (int n = 0; n < 2; ++n) {
      const int col = byn * 64 + wn * 32 + n * 16 + fr;
      const float bbv = bb[(size_t)e * H_DIM + col];
#pragma unroll
      for (int r = 0; r < 4; ++r) {
        const int rl = rl0 + r;
        if (rl < nrows) {
          const int tok = toks[rl];
          float s = accM[m][n][r] + bbv;
          if (SPLIT) s += accX[m][n][r] * inv;
          const float o = ae * s;
          const size_t idx = (size_t)tok * H_DIM + col;
          const float fo = hwv * o;
          if (first) dout[idx] = fo; else dout[idx] += fo;
          if (SPLIT) {
            half_t hv = (half_t)o;
            xnh[idx] = hv;
            xnl[idx] = (half_t)((o - (float)hv) * 2048.f);
          }
        }
      }
    }
  }
}

extern "C" void kernel_launch(void* const* d_in, const int* in_sizes, int n_in,
                              void* d_out, int out_size, void* d_ws, size_t ws_size,
                              hipStream_t stream) {
  const float* hs  = (const float*)d_in[0];   // (2,4096,1024)
  const float* w1  = (const float*)d_in[1];   // (3,1024,512)
  const float* b1  = (const float*)d_in[2];   // (3,512)
  const float* w2  = (const float*)d_in[3];   // (3,512,8)
  const float* b2  = (const float*)d_in[4];   // (3,8)
  const float* lea = (const float*)d_in[5];   // (3,8)
  const float* hww = (const float*)d_in[6];   // (3,)
  const float* Wb  = (const float*)d_in[7];   // (3,8,1024,1024)
  const float* bb  = (const float*)d_in[8];   // (3,8,1024)
  float* outp = (float*)d_out;

  char* ws = (char*)d_ws;
  size_t off = 0;
  half_t* Wth  = (half_t*)(ws + off); off += (size_t)NE * H_DIM * H_DIM * 2;   // per-level, reused
  half_t* Wtl  = (half_t*)(ws + off); off += (size_t)NE * H_DIM * H_DIM * 2;
  half_t* w1th = (half_t*)(ws + off); off += (size_t)NL * D_DIM * H_DIM * 2;
  half_t* w1tl = (half_t*)(ws + off); off += (size_t)NL * D_DIM * H_DIM * 2;
  half_t* xh0  = (half_t*)(ws + off); off += (size_t)N_TOK * H_DIM * 2;
  half_t* xl0  = (half_t*)(ws + off); off += (size_t)N_TOK * H_DIM * 2;
  half_t* xh1  = (half_t*)(ws + off); off += (size_t)N_TOK * H_DIM * 2;
  half_t* xl1  = (half_t*)(ws + off); off += (size_t)N_TOK * H_DIM * 2;
  float*  hbuf = (float*)(ws + off);  off += (size_t)N_TOK * D_DIM * 4;
  int*    eidx = (int*)(ws + off);    off += (size_t)N_TOK * 4;
  int*    perm = (int*)(ws + off);    off += (size_t)N_TOK * 4;
  int*    cnt  = (int*)(ws + off);    off += (size_t)NL * NE * 4;
  int*    offs = (int*)(ws + off);    off += (size_t)NL * (NE + 1) * 4;
  int*    cur  = (int*)(ws + off);    off += (size_t)NL * NE * 4;
  int*    done = (int*)(ws + off);    off += (size_t)NL * 4;
  float*  hwp  = (float*)(ws + off);  off += 16;

  init_small<<<1, 64, 0, stream>>>(hww, hwp, cnt, done);
  transpose_cvt<<<dim3(16, 8, NL), 256, 0, stream>>>(
      w1, (unsigned long long)H_DIM * D_DIM, w1th, w1tl,
      (unsigned long long)D_DIM * H_DIM, H_DIM, D_DIM);
  cvt_x_hilo<<<(N_TOK * H_DIM / 4 + 255) / 256, 256, 0, stream>>>(
      hs, xh0, xl0, N_TOK * H_DIM / 4);

  for (int l = 0; l < NL; ++l) {
    const half_t* xch = (l & 1) ? xh1 : xh0;
    const half_t* xcl = (l & 1) ? xl1 : xl0;
    half_t* xnh = (l == 2) ? (half_t*)nullptr : ((l & 1) ? xh0 : xh1);
    half_t* xnl = (l == 2) ? (half_t*)nullptr : ((l & 1) ? xl0 : xl1);
    // convert this level's W_base (hi always; lo only when split needed)
    transpose_cvt<<<dim3(16, 16, NE), 256, 0, stream>>>(
        Wb + (size_t)l * NE * H_DIM * H_DIM, (unsigned long long)H_DIM * H_DIM,
        Wth, (l < 2) ? Wtl : (half_t*)nullptr,
        (unsigned long long)H_DIM * H_DIM, H_DIM, H_DIM);
    routing_gemm<<<512, 256, 0, stream>>>(
        xch, xcl, w1th + (size_t)l * D_DIM * H_DIM, w1tl + (size_t)l * D_DIM * H_DIM,
        b1 + l * D_DIM, hbuf);
    logits_argmax<<<N_TOK / 4, 256, 0, stream>>>(
        hbuf, w2 + (size_t)l * D_DIM * NE, b2 + l * NE, eidx,
        cnt + l * NE, done + l, offs + l * (NE + 1), cur + l * NE);
    scatter_perm<<<N_TOK / 256, 256, 0, stream>>>(eidx, cur + l * NE, perm);
    if (l < 2) {
      expert_gemm<1><<<1152, 256, 0, stream>>>(
          xch, xcl, Wth, Wtl, bb + (size_t)l * NE * H_DIM,
          lea + l * NE, perm, offs + l * (NE + 1), hwp, l, outp, xnh, xnl);
    } else {
      expert_gemm<0><<<1152, 256, 0, stream>>>(
          xch, (const half_t*)nullptr, Wth, (const half_t*)nullptr,
          bb + (size_t)l * NE * H_DIM,
          lea + l * NE, perm, offs + l * (NE + 1), hwp, l, outp,
          (half_t*)nullptr, (half_t*)nullptr);
    }
  }
}

// Round 8
// 848.700 us; speedup vs baseline: 1.1040x; 1.0268x over previous
//
#include <hip/hip_runtime.h>
#include <stdint.h>

typedef _Float16 half_t;
typedef __attribute__((ext_vector_type(4))) _Float16 half4;
typedef __attribute__((ext_vector_type(8))) _Float16 half8;
typedef __attribute__((ext_vector_type(4))) float f32x4;

#define N_TOK 8192
#define H_DIM 1024
#define D_DIM 512
#define NE 8
#define NL 3

#define WAITV4 asm volatile("s_waitcnt vmcnt(4)" ::: "memory")
#define WAITV2 asm volatile("s_waitcnt vmcnt(2)" ::: "memory")
#define WAITV0 asm volatile("s_waitcnt vmcnt(0)" ::: "memory")
#define SCHEDB __builtin_amdgcn_sched_barrier(0)
#define RAWBAR __builtin_amdgcn_s_barrier()

// -------- async global->LDS, 16B per lane, linear dest --------
__device__ __forceinline__ void gload_lds16(const half_t* g, half_t* l) {
  __builtin_amdgcn_global_load_lds(
      (const __attribute__((address_space(1))) unsigned int*)g,
      (__attribute__((address_space(3))) unsigned int*)l, 16, 0, 0);
}

// -------- 256-thread 64x64 transpose+cvt tile (tile pitch 65 floats) --------
__device__ __forceinline__ void tr_tile_256(
    const float* src, half_t* oh, half_t* ol, int R, int C,
    int bx, int by, int tid, float* tile) {
  const int rt = bx * 64, ct = by * 64;
  const int r = tid >> 2, c0 = (tid & 3) * 16;
  const float* p = src + (size_t)(rt + r) * C + ct + c0;
#pragma unroll
  for (int q = 0; q < 4; ++q) {
    float4 v = *(const float4*)(p + q * 4);
    tile[r * 65 + c0 + q * 4 + 0] = v.x;
    tile[r * 65 + c0 + q * 4 + 1] = v.y;
    tile[r * 65 + c0 + q * 4 + 2] = v.z;
    tile[r * 65 + c0 + q * 4 + 3] = v.w;
  }
  __syncthreads();
  const int nl = tid >> 2, k0 = (tid & 3) * 16;
  half8 hv0, hv1, lv0, lv1;
#pragma unroll
  for (int i = 0; i < 16; ++i) {
    float v = tile[(k0 + i) * 65 + nl];
    half_t h = (half_t)v;
    half_t lo = (half_t)((v - (float)h) * 2048.f);
    if (i < 8) { hv0[i] = h; lv0[i] = lo; } else { hv1[i - 8] = h; lv1[i - 8] = lo; }
  }
  half_t* dst = oh + (size_t)(ct + nl) * R + rt + k0;
  *(half8*)dst = hv0;
  *(half8*)(dst + 8) = hv1;
  if (ol) {
    half_t* dl = ol + (size_t)(ct + nl) * R + rt + k0;
    *(half8*)dl = lv0;
    *(half8*)(dl + 8) = lv1;
  }
}

// -------- prep: init + w1 transpose + W[0] transpose + cvt_x, one kernel --------
// blocks: [0]=init, [1,385)=w1t (16x8x3), [385,2433)=W0t (16x16x8), [2433,3457)=cvt_x
__global__ __launch_bounds__(256) void prep(
    const float* __restrict__ hww, float* __restrict__ hwp,
    int* __restrict__ cnt, int* __restrict__ done,
    const float* __restrict__ w1, half_t* __restrict__ w1th, half_t* __restrict__ w1tl,
    const float* __restrict__ Wb0, half_t* __restrict__ Wth0, half_t* __restrict__ Wtl0,
    const float* __restrict__ hs, half_t* __restrict__ xh0, half_t* __restrict__ xl0) {
  __shared__ float tile[64 * 65];
  const int bid = blockIdx.x, tid = threadIdx.x;
  if (bid == 0) {
    if (tid < NL * NE) cnt[tid] = 0;
    if (tid < NL) done[tid] = 0;
    if (tid == 0) {
      float m = fmaxf(fmaxf(hww[0], hww[1]), hww[2]);
      float e0 = expf(hww[0] - m), e1 = expf(hww[1] - m), e2 = expf(hww[2] - m);
      float s = e0 + e1 + e2;
      hwp[0] = e0 / s; hwp[1] = e1 / s; hwp[2] = e2 / s;
    }
    return;
  }
  if (bid < 385) {
    const int t = bid - 1;
    const int bx = t & 15, by = (t >> 4) & 7, bz = t >> 7;
    tr_tile_256(w1 + (size_t)bz * H_DIM * D_DIM,
                w1th + (size_t)bz * D_DIM * H_DIM,
                w1tl + (size_t)bz * D_DIM * H_DIM,
                H_DIM, D_DIM, bx, by, tid, tile);
    return;
  }
  if (bid < 2433) {
    const int t = bid - 385;
    const int bx = t & 15, by = (t >> 4) & 15, bz = t >> 8;
    tr_tile_256(Wb0 + (size_t)bz * H_DIM * H_DIM,
                Wth0 + (size_t)bz * H_DIM * H_DIM,
                Wtl0 + (size_t)bz * H_DIM * H_DIM,
                H_DIM, H_DIM, bx, by, tid, tile);
    return;
  }
  int i = (bid - 2433) * 256 + tid;
  const int total = N_TOK * H_DIM / 4, stride = 1024 * 256;
  for (; i < total; i += stride) {
    float4 v = ((const float4*)hs)[i];
    float vv[4] = {v.x, v.y, v.z, v.w};
    half4 hv, lv;
#pragma unroll
    for (int j = 0; j < 4; ++j) {
      half_t h = (half_t)vv[j];
      hv[j] = h;
      lv[j] = (half_t)((vv[j] - (float)h) * 2048.f);
    }
    ((half4*)xh0)[i] = hv;
    ((half4*)xl0)[i] = lv;
  }
}

// -------- router GEMM: h = relu(x @ w1 + b1), fp16-split 3-pass MFMA --------
// BM=128 BN=128 BK=32, 512 thr (8 waves 2x4), 2-buf counted vmcnt, swizzled LDS.
// buffer (elems): Ah[0,4096) Al[4096,8192) Bh[8192,12288) Bl[12288,16384)
__global__ __launch_bounds__(512, 4) void routing_gemm(
    const half_t* __restrict__ xh, const half_t* __restrict__ xl,
    const half_t* __restrict__ wh, const half_t* __restrict__ wl,
    const float* __restrict__ b1, float* __restrict__ hout) {
  __shared__ __align__(16) half_t lds[2 * 16384];
  const int tid = threadIdx.x;
  const int lane = tid & 63, wv = tid >> 6;
  const int wm = wv >> 2, wn = wv & 3;
  const int lid = ((int)blockIdx.x & 7) * 32 + ((int)blockIdx.x >> 3);
  const int nt = lid & 3, mt = lid >> 2;

  const int srow = tid >> 2;
  const int skc = (((tid & 3) ^ ((tid >> 2) & 3) ^ ((tid >> 4) & 3)) * 8);
  const half_t* gAh = xh + (size_t)(mt * 128 + srow) * H_DIM + skc;
  const half_t* gAl = xl + (size_t)(mt * 128 + srow) * H_DIM + skc;
  const half_t* gBh = wh + (size_t)(nt * 128 + srow) * H_DIM + skc;
  const half_t* gBl = wl + (size_t)(nt * 128 + srow) * H_DIM + skc;

  f32x4 accM[4][2], accX[4][2];
#pragma unroll
  for (int m = 0; m < 4; ++m)
#pragma unroll
    for (int n = 0; n < 2; ++n) {
      accM[m][n] = {0.f, 0.f, 0.f, 0.f};
      accX[m][n] = {0.f, 0.f, 0.f, 0.f};
    }

  const int fr = lane & 15, fg = lane >> 4;
  const int fgs = fg ^ ((fr & 3) ^ ((fr >> 2) & 3));
  const int aoff = (wm * 64 + fr) * 32 + fgs * 8;
  const int boff = 8192 + (wn * 32 + fr) * 32 + fgs * 8;

#define R_STAGE(bo, kk) do { \
    const int go_ = (kk) * 32; \
    gload_lds16(gAh + go_, lds + (bo) + tid * 8); \
    gload_lds16(gAl + go_, lds + (bo) + 4096 + tid * 8); \
    gload_lds16(gBh + go_, lds + (bo) + 8192 + tid * 8); \
    gload_lds16(gBl + go_, lds + (bo) + 12288 + tid * 8); \
  } while (0)

  R_STAGE(0, 0);
  for (int k = 0; k < 32; ++k) {
    if (k + 1 < 32) R_STAGE(((k + 1) & 1) * 16384, k + 1);
    if (k < 31) { WAITV4; } else { WAITV0; }
    SCHEDB;
    RAWBAR;
    SCHEDB;
    const int cb = (k & 1) * 16384;
    half8 a_h[4], a_l[4], b_h[2], b_l[2];
#pragma unroll
    for (int m = 0; m < 4; ++m) {
      a_h[m] = *(const half8*)&lds[cb + aoff + m * 512];
      a_l[m] = *(const half8*)&lds[cb + 4096 + aoff + m * 512];
    }
#pragma unroll
    for (int n = 0; n < 2; ++n) {
      b_h[n] = *(const half8*)&lds[cb + boff + n * 512];
      b_l[n] = *(const half8*)&lds[cb + 4096 + boff + n * 512];
    }
    __builtin_amdgcn_s_setprio(1);
#pragma unroll
    for (int m = 0; m < 4; ++m)
#pragma unroll
      for (int n = 0; n < 2; ++n) {
        accM[m][n] = __builtin_amdgcn_mfma_f32_16x16x32_f16(a_h[m], b_h[n], accM[m][n], 0, 0, 0);
        accX[m][n] = __builtin_amdgcn_mfma_f32_16x16x32_f16(a_h[m], b_l[n], accX[m][n], 0, 0, 0);
        accX[m][n] = __builtin_amdgcn_mfma_f32_16x16x32_f16(a_l[m], b_h[n], accX[m][n], 0, 0, 0);
      }
    __builtin_amdgcn_s_setprio(0);
    SCHEDB;
    RAWBAR;
    SCHEDB;
  }
#undef R_STAGE

  const float inv = 1.0f / 2048.0f;
#pragma unroll
  for (int m = 0; m < 4; ++m) {
    const int row0 = mt * 128 + wm * 64 + m * 16 + fg * 4;
#pragma unroll
    for (int n = 0; n < 2; ++n) {
      const int col = nt * 128 + wn * 32 + n * 16 + fr;
      const float bv = b1[col];
#pragma unroll
      for (int r = 0; r < 4; ++r) {
        float v = accM[m][n][r] + accX[m][n][r] * inv + bv;
        hout[(size_t)(row0 + r) * D_DIM + col] = fmaxf(v, 0.f);
      }
    }
  }
}

// -------- logits + argmax + per-expert count; one wave per token --------
// Last block (device-scope ticket) computes the 8-bin scan -> offs/cur.
__global__ void logits_argmax(const float* __restrict__ hbuf, const float* __restrict__ w2,
                              const float* __restrict__ b2, int* __restrict__ eidx,
                              int* __restrict__ cnt, int* __restrict__ done,
                              int* __restrict__ offs, int* __restrict__ cur) {
  const int tid = threadIdx.x, lane = tid & 63, wv = tid >> 6;
  const int t = blockIdx.x * 4 + wv;
  const float* hr = hbuf + (size_t)t * D_DIM;
  float4 h0 = *(const float4*)(hr + lane * 8);
  float4 h1 = *(const float4*)(hr + lane * 8 + 4);
  float p[8] = {0, 0, 0, 0, 0, 0, 0, 0};
  const float* wr = w2 + (size_t)lane * 8 * 8;
  float hv[8] = {h0.x, h0.y, h0.z, h0.w, h1.x, h1.y, h1.z, h1.w};
#pragma unroll
  for (int j = 0; j < 8; ++j) {
    float4 wa = *(const float4*)(wr + j * 8);
    float4 wb = *(const float4*)(wr + j * 8 + 4);
    p[0] += hv[j] * wa.x; p[1] += hv[j] * wa.y; p[2] += hv[j] * wa.z; p[3] += hv[j] * wa.w;
    p[4] += hv[j] * wb.x; p[5] += hv[j] * wb.y; p[6] += hv[j] * wb.z; p[7] += hv[j] * wb.w;
  }
#pragma unroll
  for (int o = 32; o > 0; o >>= 1) {
#pragma unroll
    for (int e = 0; e < 8; ++e) p[e] += __shfl_xor(p[e], o, 64);
  }
  if (lane == 0) {
    int best = 0;
    float bvv = p[0] + b2[0];
#pragma unroll
    for (int e = 1; e < 8; ++e) {
      float v = p[e] + b2[e];
      if (v > bvv) { bvv = v; best = e; }
    }
    eidx[t] = best;
    atomicAdd(&cnt[best], 1);
  }
  __syncthreads();
  if (tid == 0) {
    __threadfence();
    int tix = atomicAdd(done, 1);
    if (tix == (int)gridDim.x - 1) {
      int a = 0;
#pragma unroll
      for (int i = 0; i < 8; ++i) { offs[i] = a; cur[i] = a; a += cnt[i]; }
      offs[8] = a;
      __threadfence();
    }
  }
}

__global__ void scatter_perm(const int* __restrict__ eidx, int* __restrict__ cur,
                             int* __restrict__ perm) {
  int t = blockIdx.x * blockDim.x + threadIdx.x;
  if (t < N_TOK) {
    int p = atomicAdd(&cur[eidx[t]], 1);
    perm[p] = t;
  }
}

// -------- expert GEMM + (optional) fused transpose of next level's W --------
// BM=128 BN=128 BK=32, 512 thr (8 waves 2x4); blocks [0,576)=GEMM,
// [576,2624)=transpose W_next (only when FUSET=1).
// SPLIT=1 buffer: Ah[0,4096) Al[4096,8192) Bh[8192,12288) Bl[12288,16384)
// SPLIT=0 buffer: Ah[0,4096) Bh[4096,8192)
template <int SPLIT, int FUSET>
__global__ __launch_bounds__(512, 4) void expert_gemm(
    const half_t* __restrict__ xh, const half_t* __restrict__ xl,
    const half_t* __restrict__ Wth, const half_t* __restrict__ Wtl,
    const float* __restrict__ bb, const float* __restrict__ asg,
    const int* __restrict__ perm, const int* __restrict__ offs,
    const float* __restrict__ hwp, const int lvl,
    float* __restrict__ dout, half_t* __restrict__ xnh, half_t* __restrict__ xnl,
    const float* __restrict__ WbN, half_t* __restrict__ WthN, half_t* __restrict__ WtlN) {
  constexpr int BUF = SPLIT ? 16384 : 8192;
  constexpr int OBH = SPLIT ? 8192 : 4096;
  __shared__ __align__(16) half_t lds[2 * BUF];
  __shared__ int toks[128];
  const int tid = threadIdx.x;

  if (FUSET && (int)blockIdx.x >= 576) {
    // 512-thread 64x64 transpose+cvt of next level's W_base
    float* tile = (float*)lds;  // [64][65]
    const int tb = (int)blockIdx.x - 576;
    const int bx = tb & 15, by = (tb >> 4) & 15, bz = tb >> 8;
    const size_t zo = (size_t)bz * H_DIM * H_DIM;
    const int rt = bx * 64, ct = by * 64;
    const int r = tid >> 3, c0 = (tid & 7) * 8;
    const float* p = WbN + zo + (size_t)(rt + r) * H_DIM + ct + c0;
    float4 va = *(const float4*)p;
    float4 vb = *(const float4*)(p + 4);
    tile[r * 65 + c0 + 0] = va.x; tile[r * 65 + c0 + 1] = va.y;
    tile[r * 65 + c0 + 2] = va.z; tile[r * 65 + c0 + 3] = va.w;
    tile[r * 65 + c0 + 4] = vb.x; tile[r * 65 + c0 + 5] = vb.y;
    tile[r * 65 + c0 + 6] = vb.z; tile[r * 65 + c0 + 7] = vb.w;
    __syncthreads();
    const int nl = tid >> 3, k0 = (tid & 7) * 8;
    half8 hvv, lvv;
#pragma unroll
    for (int i = 0; i < 8; ++i) {
      float v = tile[(k0 + i) * 65 + nl];
      half_t h = (half_t)v;
      hvv[i] = h;
      lvv[i] = (half_t)((v - (float)h) * 2048.f);
    }
    half_t* dst = WthN + zo + (size_t)(ct + nl) * H_DIM + rt + k0;
    *(half8*)dst = hvv;
    if (WtlN) {
      half_t* dl = WtlN + zo + (size_t)(ct + nl) * H_DIM + rt + k0;
      *(half8*)dl = lvv;
    }
    return;
  }

  // ---- GEMM part: bid in [0,576), XCD-chunked (72 lids/XCD = 9 tok-tiles x 8 N) ----
  const int lid = ((int)blockIdx.x & 7) * 72 + ((int)blockIdx.x >> 3);
  const int byn = lid & 7;
  const int bxt = lid >> 3;
  int e = -1, base = 0, nrows = 0, acc_t = 0;
#pragma unroll
  for (int i = 0; i < 8; ++i) {
    int s = offs[i], t2 = offs[i + 1];
    int ntl = (t2 - s + 127) >> 7;
    if (e < 0 && bxt < acc_t + ntl) {
      e = i;
      base = s + (bxt - acc_t) * 128;
      nrows = t2 - base;
      if (nrows > 128) nrows = 128;
    }
    acc_t += ntl;
  }
  if (e < 0) return;
  if (tid < 128) toks[tid] = (tid < nrows) ? perm[base + tid] : perm[base];
  __syncthreads();
  const int arow = tid >> 2;
  const int skc = (((tid & 3) ^ ((tid >> 2) & 3) ^ ((tid >> 4) & 3)) * 8);
  const int tokA = toks[arow];
  const half_t* gAh = xh + (size_t)tokA * H_DIM + skc;
  const half_t* gAl = SPLIT ? (xl + (size_t)tokA * H_DIM + skc) : nullptr;
  const size_t bg = (size_t)e * H_DIM * H_DIM + (size_t)(byn * 128 + arow) * H_DIM + skc;
  const half_t* gBh = Wth + bg;
  const half_t* gBl = SPLIT ? (Wtl + bg) : nullptr;

  f32x4 accM[4][2], accX[4][2];
#pragma unroll
  for (int m = 0; m < 4; ++m)
#pragma unroll
    for (int n = 0; n < 2; ++n) {
      accM[m][n] = {0.f, 0.f, 0.f, 0.f};
      accX[m][n] = {0.f, 0.f, 0.f, 0.f};
    }

  const int lane = tid & 63, wv = tid >> 6, wm = wv >> 2, wn = wv & 3;
  const int fr = lane & 15, fg = lane >> 4;
  const int fgs = fg ^ ((fr & 3) ^ ((fr >> 2) & 3));
  const int aoff = (wm * 64 + fr) * 32 + fgs * 8;
  const int boff = OBH + (wn * 32 + fr) * 32 + fgs * 8;

#define E_STAGE(bo, kk) do { \
    const int go_ = (kk) * 32; \
    gload_lds16(gAh + go_, lds + (bo) + tid * 8); \
    gload_lds16(gBh + go_, lds + (bo) + OBH + tid * 8); \
    if (SPLIT) { \
      gload_lds16(gAl + go_, lds + (bo) + 4096 + tid * 8); \
      gload_lds16(gBl + go_, lds + (bo) + OBH + 4096 + tid * 8); \
    } \
  } while (0)

  E_STAGE(0, 0);
  for (int k = 0; k < 32; ++k) {
    if (k + 1 < 32) E_STAGE(((k + 1) & 1) * BUF, k + 1);
    if (k < 31) { if (SPLIT) { WAITV4; } else { WAITV2; } } else { WAITV0; }
    SCHEDB;
    RAWBAR;
    SCHEDB;
    const int cb = (k & 1) * BUF;
    half8 a_h[4], b_h[2], a_l[4], b_l[2];
#pragma unroll
    for (int m = 0; m < 4; ++m) {
      a_h[m] = *(const half8*)&lds[cb + aoff + m * 512];
      if (SPLIT) a_l[m] = *(const half8*)&lds[cb + 4096 + aoff + m * 512];
    }
#pragma unroll
    for (int n = 0; n < 2; ++n) {
      b_h[n] = *(const half8*)&lds[cb + boff + n * 512];
      if (SPLIT) b_l[n] = *(const half8*)&lds[cb + 4096 + boff + n * 512];
    }
    __builtin_amdgcn_s_setprio(1);
#pragma unroll
    for (int m = 0; m < 4; ++m)
#pragma unroll
      for (int n = 0; n < 2; ++n) {
        accM[m][n] = __builtin_amdgcn_mfma_f32_16x16x32_f16(a_h[m], b_h[n], accM[m][n], 0, 0, 0);
        if (SPLIT) {
          accX[m][n] = __builtin_amdgcn_mfma_f32_16x16x32_f16(a_h[m], b_l[n], accX[m][n], 0, 0, 0);
          accX[m][n] = __builtin_amdgcn_mfma_f32_16x16x32_f16(a_l[m], b_h[n], accX[m][n], 0, 0, 0);
        }
      }
    __builtin_amdgcn_s_setprio(0);
    SCHEDB;
    RAWBAR;
    SCHEDB;
  }
#undef E_STAGE

  const float ae = asg[e];
  const float hwv = hwp[lvl];
  const float inv = 1.0f / 2048.0f;
  const bool first = (lvl == 0);
#pragma unroll
  for (int m = 0; m < 4; ++m) {
    const int rl0 = wm * 64 + m * 16 + fg * 4;
#pragma unroll
    for (int n = 0; n < 2; ++n) {
      const int col = byn * 128 + wn * 32 + n * 16 + fr;
      const float bbv = bb[(size_t)e * H_DIM + col];
#pragma unroll
      for (int r = 0; r < 4; ++r) {
        const int rl = rl0 + r;
        if (rl < nrows) {
          const int tok = toks[rl];
          float s = accM[m][n][r] + bbv;
          if (SPLIT) s += accX[m][n][r] * inv;
          const float o = ae * s;
          const size_t idx = (size_t)tok * H_DIM + col;
          const float fo = hwv * o;
          if (first) dout[idx] = fo; else dout[idx] += fo;
          if (SPLIT) {
            half_t hv = (half_t)o;
            xnh[idx] = hv;
            xnl[idx] = (half_t)((o - (float)hv) * 2048.f);
          }
        }
      }
    }
  }
}

extern "C" void kernel_launch(void* const* d_in, const int* in_sizes, int n_in,
                              void* d_out, int out_size, void* d_ws, size_t ws_size,
                              hipStream_t stream) {
  const float* hs  = (const float*)d_in[0];   // (2,4096,1024)
  const float* w1  = (const float*)d_in[1];   // (3,1024,512)
  const float* b1  = (const float*)d_in[2];   // (3,512)
  const float* w2  = (const float*)d_in[3];   // (3,512,8)
  const float* b2  = (const float*)d_in[4];   // (3,8)
  const float* lea = (const float*)d_in[5];   // (3,8)
  const float* hww = (const float*)d_in[6];   // (3,)
  const float* Wb  = (const float*)d_in[7];   // (3,8,1024,1024)
  const float* bb  = (const float*)d_in[8];   // (3,8,1024)
  float* outp = (float*)d_out;

  char* ws = (char*)d_ws;
  size_t off = 0;
  half_t* WthA = (half_t*)(ws + off); off += (size_t)NE * H_DIM * H_DIM * 2;
  half_t* WtlA = (half_t*)(ws + off); off += (size_t)NE * H_DIM * H_DIM * 2;
  half_t* WthB = (half_t*)(ws + off); off += (size_t)NE * H_DIM * H_DIM * 2;
  half_t* WtlB = (half_t*)(ws + off); off += (size_t)NE * H_DIM * H_DIM * 2;
  half_t* w1th = (half_t*)(ws + off); off += (size_t)NL * D_DIM * H_DIM * 2;
  half_t* w1tl = (half_t*)(ws + off); off += (size_t)NL * D_DIM * H_DIM * 2;
  half_t* xh0  = (half_t*)(ws + off); off += (size_t)N_TOK * H_DIM * 2;
  half_t* xl0  = (half_t*)(ws + off); off += (size_t)N_TOK * H_DIM * 2;
  half_t* xh1  = (half_t*)(ws + off); off += (size_t)N_TOK * H_DIM * 2;
  half_t* xl1  = (half_t*)(ws + off); off += (size_t)N_TOK * H_DIM * 2;
  float*  hbuf = (float*)(ws + off);  off += (size_t)N_TOK * D_DIM * 4;
  int*    eidx = (int*)(ws + off);    off += (size_t)N_TOK * 4;
  int*    perm = (int*)(ws + off);    off += (size_t)N_TOK * 4;
  int*    cnt  = (int*)(ws + off);    off += (size_t)NL * NE * 4;
  int*    offs = (int*)(ws + off);    off += (size_t)NL * (NE + 1) * 4;
  int*    cur  = (int*)(ws + off);    off += (size_t)NL * NE * 4;
  int*    done = (int*)(ws + off);    off += (size_t)NL * 4;
  float*  hwp  = (float*)(ws + off);  off += 16;

  prep<<<3457, 256, 0, stream>>>(hww, hwp, cnt, done, w1, w1th, w1tl,
                                 Wb, WthA, WtlA, hs, xh0, xl0);

  for (int l = 0; l < NL; ++l) {
    const half_t* xch = (l & 1) ? xh1 : xh0;
    const half_t* xcl = (l & 1) ? xl1 : xl0;
    half_t* xnh = (l == 2) ? (half_t*)nullptr : ((l & 1) ? xh0 : xh1);
    half_t* xnl = (l == 2) ? (half_t*)nullptr : ((l & 1) ? xl0 : xl1);
    routing_gemm<<<256, 512, 0, stream>>>(
        xch, xcl, w1th + (size_t)l * D_DIM * H_DIM, w1tl + (size_t)l * D_DIM * H_DIM,
        b1 + l * D_DIM, hbuf);
    logits_argmax<<<N_TOK / 4, 256, 0, stream>>>(
        hbuf, w2 + (size_t)l * D_DIM * NE, b2 + l * NE, eidx,
        cnt + l * NE, done + l, offs + l * (NE + 1), cur + l * NE);
    scatter_perm<<<N_TOK / 256, 256, 0, stream>>>(eidx, cur + l * NE, perm);
    if (l == 0) {
      expert_gemm<1, 1><<<2624, 512, 0, stream>>>(
          xch, xcl, WthA, WtlA, bb + (size_t)l * NE * H_DIM,
          lea + l * NE, perm, offs + l * (NE + 1), hwp, l, outp, xnh, xnl,
          Wb + (size_t)1 * NE * H_DIM * H_DIM, WthB, WtlB);
    } else if (l == 1) {
      expert_gemm<1, 1><<<2624, 512, 0, stream>>>(
          xch, xcl, WthB, WtlB, bb + (size_t)l * NE * H_DIM,
          lea + l * NE, perm, offs + l * (NE + 1), hwp, l, outp, xnh, xnl,
          Wb + (size_t)2 * NE * H_DIM * H_DIM, WthA, (half_t*)nullptr);
    } else {
      expert_gemm<0, 0><<<576, 512, 0, stream>>>(
          xch, (const half_t*)nullptr, WthA, (const half_t*)nullptr,
          bb + (size_t)l * NE * H_DIM,
          lea + l * NE, perm, offs + l * (NE + 1), hwp, l, outp,
          (half_t*)nullptr, (half_t*)nullptr,
          (const float*)nullptr, (half_t*)nullptr, (half_t*)nullptr);
    }
  }
}